// Round 1
// baseline (4186.777 us; speedup 1.0000x reference)
//
#include <hip/hip_runtime.h>

#define COL_DIM 4096
#define ROW_DIM 1024
#define NUM_LAYERS 3
#define KNN_E 16384
#define GENET_E 131072

// ---------------- transpose: in[R][C] -> out[C][R] ----------------
__global__ void transpose_kernel(const float* __restrict__ in, float* __restrict__ out,
                                 int R, int C) {
  __shared__ float tile[32][33];
  int c0 = blockIdx.x * 32, r0 = blockIdx.y * 32;
  int tx = threadIdx.x, ty = threadIdx.y; // 32 x 8
#pragma unroll
  for (int i = 0; i < 32; i += 8)
    tile[ty + i][tx] = in[(size_t)(r0 + ty + i) * C + c0 + tx];
  __syncthreads();
#pragma unroll
  for (int i = 0; i < 32; i += 8)
    out[(size_t)(c0 + ty + i) * R + r0 + tx] = tile[tx][ty + i];
}

// ---------------- CSR build ----------------
__global__ void count_kernel(const int* __restrict__ dst, int E, int* __restrict__ cnt) {
  int e = blockIdx.x * 256 + threadIdx.x;
  if (e < E) atomicAdd(&cnt[dst[e]], 1);
}

__global__ void scan_kernel(const int* __restrict__ cnt, int* __restrict__ indptr, int n) {
  __shared__ int s[1024];
  __shared__ int base_s;
  int tid = threadIdx.x;
  if (tid == 0) { base_s = 0; indptr[0] = 0; }
  __syncthreads();
  for (int c = 0; c < n; c += 1024) {
    int i = c + tid;
    int v = (i < n) ? cnt[i] : 0;
    s[tid] = v;
    __syncthreads();
    for (int off = 1; off < 1024; off <<= 1) {
      int t = (tid >= off) ? s[tid - off] : 0;
      __syncthreads();
      s[tid] += t;
      __syncthreads();
    }
    if (i < n) indptr[i + 1] = base_s + s[tid];
    __syncthreads();
    if (tid == 0) base_s += s[1023];
    __syncthreads();
  }
}

__global__ void copy_int_kernel(const int* __restrict__ a, int* __restrict__ b, int n) {
  int i = blockIdx.x * 256 + threadIdx.x;
  if (i < n) b[i] = a[i];
}

__global__ void fill_kernel(const int* __restrict__ src, const int* __restrict__ dst, int E,
                            int* __restrict__ cursor, int* __restrict__ idx) {
  int e = blockIdx.x * 256 + threadIdx.x;
  if (e < E) {
    int p = atomicAdd(&cursor[dst[e]], 1);
    idx[p] = src[e];
  }
}

// deterministic per-bucket order (bit-exact sums regardless of fill race)
__global__ void sort_kernel(const int* __restrict__ indptr, int* __restrict__ idx, int n) {
  int d = blockIdx.x * 256 + threadIdx.x;
  if (d >= n) return;
  int lo = indptr[d], hi = indptr[d + 1];
  for (int i = lo + 1; i < hi; i++) {
    int v = idx[i];
    int j = i - 1;
    while (j >= lo && idx[j] > v) { idx[j + 1] = idx[j]; j--; }
    idx[j + 1] = v;
  }
}

// ---------------- neighbor mean: out[d][k] = mean_{s in N(d)} src[s][k] ----------------
__global__ void agg_mean_kernel(const float* __restrict__ src, float* __restrict__ out,
                                const int* __restrict__ indptr, const int* __restrict__ idx,
                                int D) {
  int k = blockIdx.x * 256 + threadIdx.x;
  int d = blockIdx.y;
  int lo = indptr[d], hi = indptr[d + 1];
  float s = 0.f;
  for (int j = lo; j < hi; j++) s += src[(size_t)idx[j] * D + k];
  int c = hi - lo;
  out[(size_t)d * D + k] = s / (float)(c > 0 ? c : 1);
}

// ---------------- fused dual NT GEMM ----------------
// C[m][n] = leaky( sum_k A1[m][k]*B1[n][k] + sum_k A2[m][k]*B2[n][k] + bias )
// A*: [M][K] row-major, B*: [N][K] row-major, C: [M][N] row-major.
// biasPerRow!=0 -> bias[m], else bias[n].
#define BM 128
#define BN 128
#define BK 16
#define LDA (BM + 8)
#define LDB (BN + 8)

#define LSTORE(S, v, r, c4)                                                    \
  S[(c4) + 0][r] = (v).x;                                                      \
  S[(c4) + 1][r] = (v).y;                                                      \
  S[(c4) + 2][r] = (v).z;                                                      \
  S[(c4) + 3][r] = (v).w;

__global__ __launch_bounds__(256) void dual_nt_gemm_kernel(
    const float* __restrict__ A1, const float* __restrict__ B1,
    const float* __restrict__ A2, const float* __restrict__ B2,
    const float* __restrict__ bias, float* __restrict__ C,
    int N, int K, int biasPerRow) {
  __shared__ float As1[BK][LDA], As2[BK][LDA], Bs1[BK][LDB], Bs2[BK][LDB];
  const int tid = threadIdx.x;
  const int bn0 = blockIdx.x * BN;
  const int bm0 = blockIdx.y * BM;
  const int tx = tid & 15, ty = tid >> 4;

  // global-load mapping: 512 float4 per tile, 2 per thread
  const int r0 = tid >> 2, c40 = (tid & 3) * 4;
  const int r1 = (tid + 256) >> 2, c41 = ((tid + 256) & 3) * 4;

  float acc[8][8];
#pragma unroll
  for (int i = 0; i < 8; i++)
#pragma unroll
    for (int j = 0; j < 8; j++) acc[i][j] = 0.f;

  float4 pa1[2], pa2[2], pb1[2], pb2[2];

#define GLOADS(k0)                                                             \
  pa1[0] = *(const float4*)(A1 + (size_t)(bm0 + r0) * K + (k0) + c40);         \
  pa1[1] = *(const float4*)(A1 + (size_t)(bm0 + r1) * K + (k0) + c41);         \
  pa2[0] = *(const float4*)(A2 + (size_t)(bm0 + r0) * K + (k0) + c40);         \
  pa2[1] = *(const float4*)(A2 + (size_t)(bm0 + r1) * K + (k0) + c41);         \
  pb1[0] = *(const float4*)(B1 + (size_t)(bn0 + r0) * K + (k0) + c40);         \
  pb1[1] = *(const float4*)(B1 + (size_t)(bn0 + r1) * K + (k0) + c41);         \
  pb2[0] = *(const float4*)(B2 + (size_t)(bn0 + r0) * K + (k0) + c40);         \
  pb2[1] = *(const float4*)(B2 + (size_t)(bn0 + r1) * K + (k0) + c41);

  GLOADS(0);

  const int ntiles = K / BK;
  for (int t = 0; t < ntiles; t++) {
    __syncthreads();
    LSTORE(As1, pa1[0], r0, c40);
    LSTORE(As1, pa1[1], r1, c41);
    LSTORE(As2, pa2[0], r0, c40);
    LSTORE(As2, pa2[1], r1, c41);
    LSTORE(Bs1, pb1[0], r0, c40);
    LSTORE(Bs1, pb1[1], r1, c41);
    LSTORE(Bs2, pb2[0], r0, c40);
    LSTORE(Bs2, pb2[1], r1, c41);
    __syncthreads();
    if (t + 1 < ntiles) {
      GLOADS((t + 1) * BK);
    }
#pragma unroll
    for (int kk = 0; kk < BK; kk++) {
      float4 a0 = *(const float4*)&As1[kk][ty * 4];
      float4 a1 = *(const float4*)&As1[kk][ty * 4 + 64];
      float4 b0 = *(const float4*)&Bs1[kk][tx * 4];
      float4 b1 = *(const float4*)&Bs1[kk][tx * 4 + 64];
      {
        float av[8] = {a0.x, a0.y, a0.z, a0.w, a1.x, a1.y, a1.z, a1.w};
        float bv[8] = {b0.x, b0.y, b0.z, b0.w, b1.x, b1.y, b1.z, b1.w};
#pragma unroll
        for (int i2 = 0; i2 < 8; i2++)
#pragma unroll
          for (int j2 = 0; j2 < 8; j2++) acc[i2][j2] += av[i2] * bv[j2];
      }
      a0 = *(const float4*)&As2[kk][ty * 4];
      a1 = *(const float4*)&As2[kk][ty * 4 + 64];
      b0 = *(const float4*)&Bs2[kk][tx * 4];
      b1 = *(const float4*)&Bs2[kk][tx * 4 + 64];
      {
        float av[8] = {a0.x, a0.y, a0.z, a0.w, a1.x, a1.y, a1.z, a1.w};
        float bv[8] = {b0.x, b0.y, b0.z, b0.w, b1.x, b1.y, b1.z, b1.w};
#pragma unroll
        for (int i2 = 0; i2 < 8; i2++)
#pragma unroll
          for (int j2 = 0; j2 < 8; j2++) acc[i2][j2] += av[i2] * bv[j2];
      }
    }
  }

  // epilogue: bias + leaky relu + store
#pragma unroll
  for (int ih = 0; ih < 2; ih++) {
#pragma unroll
    for (int i = 0; i < 4; i++) {
      int m = bm0 + ih * 64 + ty * 4 + i;
      float brow = biasPerRow ? bias[m] : 0.f;
#pragma unroll
      for (int jh = 0; jh < 2; jh++) {
        int n = bn0 + jh * 64 + tx * 4;
        float4 v;
        v.x = acc[ih * 4 + i][jh * 4 + 0] + (biasPerRow ? brow : bias[n + 0]);
        v.y = acc[ih * 4 + i][jh * 4 + 1] + (biasPerRow ? brow : bias[n + 1]);
        v.z = acc[ih * 4 + i][jh * 4 + 2] + (biasPerRow ? brow : bias[n + 2]);
        v.w = acc[ih * 4 + i][jh * 4 + 3] + (biasPerRow ? brow : bias[n + 3]);
        v.x = v.x > 0.f ? v.x : 0.01f * v.x;
        v.y = v.y > 0.f ? v.y : 0.01f * v.y;
        v.z = v.z > 0.f ? v.z : 0.01f * v.z;
        v.w = v.w > 0.f ? v.w : 0.01f * v.w;
        *(float4*)(C + (size_t)m * N + n) = v;
      }
    }
  }
}

extern "C" void kernel_launch(void* const* d_in, const int* in_sizes, int n_in,
                              void* d_out, int out_size, void* d_ws, size_t ws_size,
                              hipStream_t stream) {
  const float* x      = (const float*)d_in[0];
  const float* col_Wl = (const float*)d_in[1];
  const float* col_Wr = (const float*)d_in[2];
  const float* col_b  = (const float*)d_in[3];
  const float* row_Wl = (const float*)d_in[4];
  const float* row_Wr = (const float*)d_in[5];
  const float* row_b  = (const float*)d_in[6];
  const int*   knn    = (const int*)d_in[7];   // [2][KNN_E]
  const int*   genet  = (const int*)d_in[8];   // [2][GENET_E]
  float* out = (float*)d_out;

  const size_t MAT = (size_t)COL_DIM * ROW_DIM; // 4M floats
  char* w = (char*)d_ws;
  float* ET   = (float*)w; w += MAT * 4;   // [1024][4096]
  float* MEAN = (float*)w; w += MAT * 4;   // shared: [1024][4096] or [4096][1024]
  float* E1   = (float*)w; w += MAT * 4;   // [4096][1024]
  int* kcnt = (int*)w; w += 1024 * 4;      // also cursor
  int* kptr = (int*)w; w += 1025 * 4;
  int* kidx = (int*)w; w += KNN_E * 4;
  int* gcnt = (int*)w; w += 4096 * 4;      // also cursor
  int* gptr = (int*)w; w += 4097 * 4;
  int* gidx = (int*)w; w += (size_t)GENET_E * 4;

  // ---- CSR build (edges fixed across layers) ----
  hipMemsetAsync(kcnt, 0, 1024 * 4, stream);
  hipMemsetAsync(gcnt, 0, 4096 * 4, stream);
  count_kernel<<<KNN_E / 256, 256, 0, stream>>>(knn + KNN_E, KNN_E, kcnt);
  count_kernel<<<GENET_E / 256, 256, 0, stream>>>(genet + GENET_E, GENET_E, gcnt);
  scan_kernel<<<1, 1024, 0, stream>>>(kcnt, kptr, 1024);
  scan_kernel<<<1, 1024, 0, stream>>>(gcnt, gptr, 4096);
  copy_int_kernel<<<4, 256, 0, stream>>>(kptr, kcnt, 1024);
  copy_int_kernel<<<16, 256, 0, stream>>>(gptr, gcnt, 4096);
  fill_kernel<<<KNN_E / 256, 256, 0, stream>>>(knn, knn + KNN_E, KNN_E, kcnt, kidx);
  fill_kernel<<<GENET_E / 256, 256, 0, stream>>>(genet, genet + GENET_E, GENET_E, gcnt, gidx);
  sort_kernel<<<4, 256, 0, stream>>>(kptr, kidx, 1024);
  sort_kernel<<<16, 256, 0, stream>>>(gptr, gidx, 4096);

  const float* Ein = x;
  for (int i = 0; i < NUM_LAYERS; i++) {
    // ET = Ein^T  : [4096][1024] -> [1024][4096]
    transpose_kernel<<<dim3(ROW_DIM / 32, COL_DIM / 32), dim3(32, 8), 0, stream>>>(
        Ein, ET, COL_DIM, ROW_DIM);
    // mean_c [1024][4096] over knn edges of ET rows
    agg_mean_kernel<<<dim3(COL_DIM / 256, ROW_DIM), 256, 0, stream>>>(
        ET, MEAN, kptr, kidx, COL_DIM);
    // E1 = leaky( Wl @ mean_c^T + Wr @ Ein + col_b )   -> [4096][1024]
    dual_nt_gemm_kernel<<<dim3(ROW_DIM / BN, COL_DIM / BM), 256, 0, stream>>>(
        col_Wl + (size_t)i * COL_DIM * COL_DIM, MEAN,
        col_Wr + (size_t)i * COL_DIM * COL_DIM, ET,
        col_b + (size_t)i * COL_DIM, E1, ROW_DIM, COL_DIM, 1);
    // mean_g [4096][1024] over genet edges of E1 rows
    agg_mean_kernel<<<dim3(ROW_DIM / 256, COL_DIM), 256, 0, stream>>>(
        E1, MEAN, gptr, gidx, ROW_DIM);
    // out = leaky( mean_g @ rWl^T + E1 @ rWr^T + row_b )  -> [4096][1024]
    dual_nt_gemm_kernel<<<dim3(ROW_DIM / BN, COL_DIM / BM), 256, 0, stream>>>(
        MEAN, row_Wl + (size_t)i * ROW_DIM * ROW_DIM,
        E1, row_Wr + (size_t)i * ROW_DIM * ROW_DIM,
        row_b + (size_t)i * ROW_DIM, out, ROW_DIM, ROW_DIM, 0);
    Ein = out;
  }
}

// Round 2
// 1785.957 us; speedup vs baseline: 2.3443x; 2.3443x over previous
//
#include <hip/hip_runtime.h>

#define COL_DIM 4096
#define ROW_DIM 1024
#define NUM_LAYERS 3
#define KNN_E 16384
#define GENET_E 131072

typedef __attribute__((ext_vector_type(8))) short short8;
typedef __attribute__((ext_vector_type(4))) float f32x4;

// ---------------- transpose: in[R][C] -> out[C][R] ----------------
__global__ void transpose_kernel(const float* __restrict__ in, float* __restrict__ out,
                                 int R, int C) {
  __shared__ float tile[32][33];
  int c0 = blockIdx.x * 32, r0 = blockIdx.y * 32;
  int tx = threadIdx.x, ty = threadIdx.y; // 32 x 8
#pragma unroll
  for (int i = 0; i < 32; i += 8)
    tile[ty + i][tx] = in[(size_t)(r0 + ty + i) * C + c0 + tx];
  __syncthreads();
#pragma unroll
  for (int i = 0; i < 32; i += 8)
    out[(size_t)(c0 + ty + i) * R + r0 + tx] = tile[tx][ty + i];
}

// ---------------- CSR build ----------------
__global__ void count_kernel(const int* __restrict__ dst, int E, int* __restrict__ cnt) {
  int e = blockIdx.x * 256 + threadIdx.x;
  if (e < E) atomicAdd(&cnt[dst[e]], 1);
}

__global__ void scan_kernel(const int* __restrict__ cnt, int* __restrict__ indptr, int n) {
  __shared__ int s[1024];
  __shared__ int base_s;
  int tid = threadIdx.x;
  if (tid == 0) { base_s = 0; indptr[0] = 0; }
  __syncthreads();
  for (int c = 0; c < n; c += 1024) {
    int i = c + tid;
    int v = (i < n) ? cnt[i] : 0;
    s[tid] = v;
    __syncthreads();
    for (int off = 1; off < 1024; off <<= 1) {
      int t = (tid >= off) ? s[tid - off] : 0;
      __syncthreads();
      s[tid] += t;
      __syncthreads();
    }
    if (i < n) indptr[i + 1] = base_s + s[tid];
    __syncthreads();
    if (tid == 0) base_s += s[1023];
    __syncthreads();
  }
}

__global__ void copy_int_kernel(const int* __restrict__ a, int* __restrict__ b, int n) {
  int i = blockIdx.x * 256 + threadIdx.x;
  if (i < n) b[i] = a[i];
}

__global__ void fill_kernel(const int* __restrict__ src, const int* __restrict__ dst, int E,
                            int* __restrict__ cursor, int* __restrict__ idx) {
  int e = blockIdx.x * 256 + threadIdx.x;
  if (e < E) {
    int p = atomicAdd(&cursor[dst[e]], 1);
    idx[p] = src[e];
  }
}

// deterministic per-bucket order (bit-exact sums regardless of fill race)
__global__ void sort_kernel(const int* __restrict__ indptr, int* __restrict__ idx, int n) {
  int d = blockIdx.x * 256 + threadIdx.x;
  if (d >= n) return;
  int lo = indptr[d], hi = indptr[d + 1];
  for (int i = lo + 1; i < hi; i++) {
    int v = idx[i];
    int j = i - 1;
    while (j >= lo && idx[j] > v) { idx[j + 1] = idx[j]; j--; }
    idx[j + 1] = v;
  }
}

// ---------------- neighbor mean ----------------
__global__ void agg_mean_kernel(const float* __restrict__ src, float* __restrict__ out,
                                const int* __restrict__ indptr, const int* __restrict__ idx,
                                int D) {
  int k = blockIdx.x * 256 + threadIdx.x;
  int d = blockIdx.y;
  int lo = indptr[d], hi = indptr[d + 1];
  float s = 0.f;
  for (int j = lo; j < hi; j++) s += src[(size_t)idx[j] * D + k];
  int c = hi - lo;
  out[(size_t)d * D + k] = s / (float)(c > 0 ? c : 1);
}

// ---------------- fp32 -> bf16 hi/lo split ----------------
__device__ inline unsigned short f2bf(float f) {
  unsigned int u = __float_as_uint(f);
  u += 0x7FFFu + ((u >> 16) & 1u); // RNE
  return (unsigned short)(u >> 16);
}
__device__ inline float bf2f(unsigned short h) {
  return __uint_as_float(((unsigned int)h) << 16);
}

__global__ void split_kernel(const float* __restrict__ src, unsigned short* __restrict__ dh,
                             unsigned short* __restrict__ dl, int n4) {
  int i = blockIdx.x * 256 + threadIdx.x;
  int stride = gridDim.x * 256;
  for (; i < n4; i += stride) {
    float4 v = ((const float4*)src)[i];
    ushort4 h, l;
    h.x = f2bf(v.x); l.x = f2bf(v.x - bf2f(h.x));
    h.y = f2bf(v.y); l.y = f2bf(v.y - bf2f(h.y));
    h.z = f2bf(v.z); l.z = f2bf(v.z - bf2f(h.z));
    h.w = f2bf(v.w); l.w = f2bf(v.w - bf2f(h.w));
    ((ushort4*)dh)[i] = h;
    ((ushort4*)dl)[i] = l;
  }
}

// ---------------- split-bf16 x3 MFMA NT GEMM ----------------
// C[m][n] (+)= sum_k A[m,k]*B[n,k], A=[4096][K] bf16 hi/lo, B=[1024][K] bf16 hi/lo.
// mode 0: C = raw partial (no bias/act). mode 1: C = leaky(C + acc + bias[row]).
// mode 2: C = leaky(C + acc + bias[col]).
#define GBM 128
#define GBN 128
#define GBK 32

#define GLDS(g, l)                                                             \
  __builtin_amdgcn_global_load_lds(                                            \
      (const __attribute__((address_space(1))) void*)(g),                      \
      (__attribute__((address_space(3))) void*)(l), 16, 0, 0)

__global__ __launch_bounds__(256, 1) void split_gemm_kernel(
    const unsigned short* __restrict__ Ah, const unsigned short* __restrict__ Al,
    const unsigned short* __restrict__ Bh, const unsigned short* __restrict__ Bl,
    const float* __restrict__ bias, float* __restrict__ C, int K, int mode) {
  // 2 buffers x {Ah,Al,Bh,Bl} x [128][32] bf16 (8KB) = 64KB
  __shared__ unsigned short sm[2][4][GBM * GBK];
  const int tid = threadIdx.x;
  const int lane = tid & 63;
  const int wid = tid >> 6;
  const int wr = wid >> 1, wc = wid & 1;

  // XCD-chunked swizzle: 256 blocks, 8 XCDs -> each XCD gets 4 consecutive
  // m-rows (A-panel L2 reuse; A is the big operand).
  const int bid = blockIdx.x;
  const int swz = (bid & 7) * 32 + (bid >> 3);
  const int bm0 = (swz >> 3) * GBM;
  const int bn0 = (swz & 7) * GBN;

  // staging: each tile = 512 units of 16B. unit u -> LDS offset u*16 (linear,
  // required by global_load_lds); global source slot = (u&3) ^ (row&3)
  // (pre-swizzled source; ds_read applies the same XOR -> involution).
  const int u0 = tid, u1 = tid + 256;
  const int r0 = u0 >> 2, r1 = u1 >> 2;
  const int c0 = ((u0 & 3) ^ (r0 & 3)) * 8;
  const int c1 = ((u1 & 3) ^ (r1 & 3)) * 8;

  const unsigned short* gAh0 = Ah + (size_t)(bm0 + r0) * K + c0;
  const unsigned short* gAh1 = Ah + (size_t)(bm0 + r1) * K + c1;
  const unsigned short* gAl0 = Al + (size_t)(bm0 + r0) * K + c0;
  const unsigned short* gAl1 = Al + (size_t)(bm0 + r1) * K + c1;
  const unsigned short* gBh0 = Bh + (size_t)(bn0 + r0) * K + c0;
  const unsigned short* gBh1 = Bh + (size_t)(bn0 + r1) * K + c1;
  const unsigned short* gBl0 = Bl + (size_t)(bn0 + r0) * K + c0;
  const unsigned short* gBl1 = Bl + (size_t)(bn0 + r1) * K + c1;

  // ds_read offsets (ushort units): frag row r, k-slot s=lane>>4,
  // unit = r*4 + (s ^ (r&3))
  int offA[4], offB[4];
#pragma unroll
  for (int i = 0; i < 4; i++) {
    int rA = wr * 64 + i * 16 + (lane & 15);
    int rB = wc * 64 + i * 16 + (lane & 15);
    int s = lane >> 4;
    offA[i] = rA * 32 + ((s ^ (rA & 3)) * 8);
    offB[i] = rB * 32 + ((s ^ (rB & 3)) * 8);
  }

  f32x4 acc[4][4];
#pragma unroll
  for (int i = 0; i < 4; i++)
#pragma unroll
    for (int j = 0; j < 4; j++) acc[i][j] = (f32x4)(0.f);

#define STAGE(buf)                                                             \
  {                                                                            \
    GLDS(gAh0, &sm[buf][0][u0 * 8]); GLDS(gAh1, &sm[buf][0][u1 * 8]);          \
    GLDS(gAl0, &sm[buf][1][u0 * 8]); GLDS(gAl1, &sm[buf][1][u1 * 8]);          \
    GLDS(gBh0, &sm[buf][2][u0 * 8]); GLDS(gBh1, &sm[buf][2][u1 * 8]);          \
    GLDS(gBl0, &sm[buf][3][u0 * 8]); GLDS(gBl1, &sm[buf][3][u1 * 8]);          \
    gAh0 += GBK; gAh1 += GBK; gAl0 += GBK; gAl1 += GBK;                        \
    gBh0 += GBK; gBh1 += GBK; gBl0 += GBK; gBl1 += GBK;                        \
  }

  const int nt = K / GBK;
  STAGE(0);
  int cur = 0;
  for (int t = 0; t < nt; t++) {
    __syncthreads(); // drains vmcnt -> sm[cur] staged; prior reads of sm[cur^1] done
    if (t + 1 < nt) STAGE(cur ^ 1); // prefetch next tile; drained at next barrier
    short8 fah[4], fal[4], fbh[4], fbl[4];
#pragma unroll
    for (int i = 0; i < 4; i++) {
      fah[i] = *(const short8*)&sm[cur][0][offA[i]];
      fal[i] = *(const short8*)&sm[cur][1][offA[i]];
      fbh[i] = *(const short8*)&sm[cur][2][offB[i]];
      fbl[i] = *(const short8*)&sm[cur][3][offB[i]];
    }
    // three sweeps (hh, hl, lh): 15 independent MFMAs between reuses of one acc
#pragma unroll
    for (int i = 0; i < 4; i++)
#pragma unroll
      for (int j = 0; j < 4; j++)
        acc[i][j] = __builtin_amdgcn_mfma_f32_16x16x32_bf16(fah[i], fbh[j], acc[i][j], 0, 0, 0);
#pragma unroll
    for (int i = 0; i < 4; i++)
#pragma unroll
      for (int j = 0; j < 4; j++)
        acc[i][j] = __builtin_amdgcn_mfma_f32_16x16x32_bf16(fah[i], fbl[j], acc[i][j], 0, 0, 0);
#pragma unroll
    for (int i = 0; i < 4; i++)
#pragma unroll
      for (int j = 0; j < 4; j++)
        acc[i][j] = __builtin_amdgcn_mfma_f32_16x16x32_bf16(fal[i], fbh[j], acc[i][j], 0, 0, 0);
    cur ^= 1;
  }

  const int rowq = (lane >> 4) * 4;
  const int colq = lane & 15;
#pragma unroll
  for (int i = 0; i < 4; i++) {
#pragma unroll
    for (int j = 0; j < 4; j++) {
#pragma unroll
      for (int q = 0; q < 4; q++) {
        int row = bm0 + wr * 64 + i * 16 + rowq + q;
        int col = bn0 + wc * 64 + j * 16 + colq;
        size_t o = (size_t)row * 1024 + col;
        float v = acc[i][j][q];
        if (mode == 0) {
          C[o] = v;
        } else {
          float x = C[o] + v + (mode == 1 ? bias[row] : bias[col]);
          C[o] = x > 0.f ? x : 0.01f * x;
        }
      }
    }
  }
}

extern "C" void kernel_launch(void* const* d_in, const int* in_sizes, int n_in,
                              void* d_out, int out_size, void* d_ws, size_t ws_size,
                              hipStream_t stream) {
  const float* x      = (const float*)d_in[0];
  const float* col_Wl = (const float*)d_in[1];
  const float* col_Wr = (const float*)d_in[2];
  const float* col_b  = (const float*)d_in[3];
  const float* row_Wl = (const float*)d_in[4];
  const float* row_Wr = (const float*)d_in[5];
  const float* row_b  = (const float*)d_in[6];
  const int*   knn    = (const int*)d_in[7];   // [2][KNN_E]
  const int*   genet  = (const int*)d_in[8];   // [2][GENET_E]
  float* out = (float*)d_out;

  const size_t MAT = (size_t)COL_DIM * ROW_DIM; // 4M floats
  char* w = (char*)d_ws;
  float* ET   = (float*)w; w += MAT * 4;              // [1024][4096] fp32
  float* MEAN = (float*)w; w += MAT * 4;              // [1024][4096] or [4096][1024]
  float* E1   = (float*)w; w += MAT * 4;              // [4096][1024] fp32
  unsigned short* SAh = (unsigned short*)w; w += (size_t)COL_DIM * COL_DIM * 2; // 32MB
  unsigned short* SAl = (unsigned short*)w; w += (size_t)COL_DIM * COL_DIM * 2; // 32MB
  unsigned short* SBh = (unsigned short*)w; w += (size_t)ROW_DIM * COL_DIM * 2; // 8MB
  unsigned short* SBl = (unsigned short*)w; w += (size_t)ROW_DIM * COL_DIM * 2; // 8MB
  int* kcnt = (int*)w; w += 1024 * 4;
  int* kptr = (int*)w; w += 1025 * 4;
  int* kidx = (int*)w; w += KNN_E * 4;
  int* gcnt = (int*)w; w += 4096 * 4;
  int* gptr = (int*)w; w += 4097 * 4;
  int* gidx = (int*)w; w += (size_t)GENET_E * 4;

  // ---- CSR build (deterministic via per-bucket sort) ----
  hipMemsetAsync(kcnt, 0, 1024 * 4, stream);
  hipMemsetAsync(gcnt, 0, 4096 * 4, stream);
  count_kernel<<<KNN_E / 256, 256, 0, stream>>>(knn + KNN_E, KNN_E, kcnt);
  count_kernel<<<GENET_E / 256, 256, 0, stream>>>(genet + GENET_E, GENET_E, gcnt);
  scan_kernel<<<1, 1024, 0, stream>>>(kcnt, kptr, 1024);
  scan_kernel<<<1, 1024, 0, stream>>>(gcnt, gptr, 4096);
  copy_int_kernel<<<4, 256, 0, stream>>>(kptr, kcnt, 1024);
  copy_int_kernel<<<16, 256, 0, stream>>>(gptr, gcnt, 4096);
  fill_kernel<<<KNN_E / 256, 256, 0, stream>>>(knn, knn + KNN_E, KNN_E, kcnt, kidx);
  fill_kernel<<<GENET_E / 256, 256, 0, stream>>>(genet, genet + GENET_E, GENET_E, gcnt, gidx);
  sort_kernel<<<4, 256, 0, stream>>>(kptr, kidx, 1024);
  sort_kernel<<<16, 256, 0, stream>>>(gptr, gidx, 4096);

  const float* Ein = x;
  for (int i = 0; i < NUM_LAYERS; i++) {
    const float* cWl = col_Wl + (size_t)i * COL_DIM * COL_DIM;
    const float* cWr = col_Wr + (size_t)i * COL_DIM * COL_DIM;
    const float* cb  = col_b + (size_t)i * COL_DIM;
    const float* rWl = row_Wl + (size_t)i * ROW_DIM * ROW_DIM;
    const float* rWr = row_Wr + (size_t)i * ROW_DIM * ROW_DIM;
    const float* rb  = row_b + (size_t)i * ROW_DIM;

    // ---- column branch: E1 = leaky(Wl@mean_c^T + Wr@Ein + cb[m]) ----
    transpose_kernel<<<dim3(ROW_DIM / 32, COL_DIM / 32), dim3(32, 8), 0, stream>>>(
        Ein, ET, COL_DIM, ROW_DIM);
    agg_mean_kernel<<<dim3(COL_DIM / 256, ROW_DIM), 256, 0, stream>>>(
        ET, MEAN, kptr, kidx, COL_DIM);
    split_kernel<<<2048, 256, 0, stream>>>(MEAN, SBh, SBl, (int)(MAT / 4));
    split_kernel<<<2048, 256, 0, stream>>>(cWl, SAh, SAl, COL_DIM * COL_DIM / 4);
    split_gemm_kernel<<<256, 256, 0, stream>>>(SAh, SAl, SBh, SBl, cb, E1, COL_DIM, 0);
    split_kernel<<<2048, 256, 0, stream>>>(ET, SBh, SBl, (int)(MAT / 4));
    split_kernel<<<2048, 256, 0, stream>>>(cWr, SAh, SAl, COL_DIM * COL_DIM / 4);
    split_gemm_kernel<<<256, 256, 0, stream>>>(SAh, SAl, SBh, SBl, cb, E1, COL_DIM, 1);

    // ---- row branch: out = leaky(mean_g@rWl^T + E1@rWr^T + rb[n]) ----
    agg_mean_kernel<<<dim3(ROW_DIM / 256, COL_DIM), 256, 0, stream>>>(
        E1, MEAN, gptr, gidx, ROW_DIM);
    split_kernel<<<2048, 256, 0, stream>>>(MEAN, SAh, SAl, (int)(MAT / 4));
    split_kernel<<<1024, 256, 0, stream>>>(rWl, SBh, SBl, ROW_DIM * ROW_DIM / 4);
    split_gemm_kernel<<<256, 256, 0, stream>>>(SAh, SAl, SBh, SBl, rb, out, ROW_DIM, 0);
    split_kernel<<<2048, 256, 0, stream>>>(E1, SAh, SAl, (int)(MAT / 4));
    split_kernel<<<1024, 256, 0, stream>>>(rWr, SBh, SBl, ROW_DIM * ROW_DIM / 4);
    split_gemm_kernel<<<256, 256, 0, stream>>>(SAh, SAl, SBh, SBl, rb, out, ROW_DIM, 2);

    Ein = out;
  }
}

// Round 3
// 1509.318 us; speedup vs baseline: 2.7740x; 1.1833x over previous
//
#include <hip/hip_runtime.h>

#define COL_DIM 4096
#define ROW_DIM 1024
#define NUM_LAYERS 3
#define KNN_E 16384
#define GENET_E 131072

typedef __attribute__((ext_vector_type(8))) short short8;
typedef __attribute__((ext_vector_type(4))) float f32x4;

// ---------------- transpose: in[R][C] -> out[C][R] ----------------
__global__ void transpose_kernel(const float* __restrict__ in, float* __restrict__ out,
                                 int R, int C) {
  __shared__ float tile[32][33];
  int c0 = blockIdx.x * 32, r0 = blockIdx.y * 32;
  int tx = threadIdx.x, ty = threadIdx.y; // 32 x 8
#pragma unroll
  for (int i = 0; i < 32; i += 8)
    tile[ty + i][tx] = in[(size_t)(r0 + ty + i) * C + c0 + tx];
  __syncthreads();
#pragma unroll
  for (int i = 0; i < 32; i += 8)
    out[(size_t)(c0 + ty + i) * R + r0 + tx] = tile[tx][ty + i];
}

// ---------------- CSR build ----------------
__global__ void count_kernel(const int* __restrict__ dst, int E, int* __restrict__ cnt) {
  int e = blockIdx.x * 256 + threadIdx.x;
  if (e < E) atomicAdd(&cnt[dst[e]], 1);
}

__global__ void scan_kernel(const int* __restrict__ cnt, int* __restrict__ indptr, int n) {
  __shared__ int s[1024];
  __shared__ int base_s;
  int tid = threadIdx.x;
  if (tid == 0) { base_s = 0; indptr[0] = 0; }
  __syncthreads();
  for (int c = 0; c < n; c += 1024) {
    int i = c + tid;
    int v = (i < n) ? cnt[i] : 0;
    s[tid] = v;
    __syncthreads();
    for (int off = 1; off < 1024; off <<= 1) {
      int t = (tid >= off) ? s[tid - off] : 0;
      __syncthreads();
      s[tid] += t;
      __syncthreads();
    }
    if (i < n) indptr[i + 1] = base_s + s[tid];
    __syncthreads();
    if (tid == 0) base_s += s[1023];
    __syncthreads();
  }
}

__global__ void copy_int_kernel(const int* __restrict__ a, int* __restrict__ b, int n) {
  int i = blockIdx.x * 256 + threadIdx.x;
  if (i < n) b[i] = a[i];
}

__global__ void fill_kernel(const int* __restrict__ src, const int* __restrict__ dst, int E,
                            int* __restrict__ cursor, int* __restrict__ idx) {
  int e = blockIdx.x * 256 + threadIdx.x;
  if (e < E) {
    int p = atomicAdd(&cursor[dst[e]], 1);
    idx[p] = src[e];
  }
}

// ---------------- wave-per-bucket rank sort (deterministic: sorted by value) ---
// rank[i] = #{j : v[j] < v[i] or (v[j]==v[i] and j<i)}; equal values are
// interchangeable so the final array is independent of fill_kernel's races.
__global__ void rank_sort_kernel(const int* __restrict__ indptr, int* __restrict__ idx,
                                 int n) {
  int wv = threadIdx.x >> 6, lane = threadIdx.x & 63;
  int b = blockIdx.x * (blockDim.x >> 6) + wv;
  if (b >= n) return;
  int lo = indptr[b];
  int d = indptr[b + 1] - lo;
  if (d <= 1) return;
  if (d <= 256) {
    int v0 = (lane < d) ? idx[lo + lane] : 0x7fffffff;
    int v1 = (64 + lane < d) ? idx[lo + 64 + lane] : 0x7fffffff;
    int v2 = (128 + lane < d) ? idx[lo + 128 + lane] : 0x7fffffff;
    int v3 = (192 + lane < d) ? idx[lo + 192 + lane] : 0x7fffffff;
    int r0 = 0, r1 = 0, r2 = 0, r3 = 0;
    for (int j = 0; j < d; j++) {
      int q = j >> 6;
      int sel = (q == 0) ? v0 : (q == 1) ? v1 : (q == 2) ? v2 : v3;
      int bj = __shfl(sel, j & 63);
      r0 += (bj < v0 || (bj == v0 && j < lane)) ? 1 : 0;
      r1 += (bj < v1 || (bj == v1 && j < 64 + lane)) ? 1 : 0;
      r2 += (bj < v2 || (bj == v2 && j < 128 + lane)) ? 1 : 0;
      r3 += (bj < v3 || (bj == v3 && j < 192 + lane)) ? 1 : 0;
    }
    if (lane < d) idx[lo + r0] = v0;
    if (64 + lane < d) idx[lo + r1] = v1;
    if (128 + lane < d) idx[lo + r2] = v2;
    if (192 + lane < d) idx[lo + r3] = v3;
  } else if (lane == 0) { // unreachable for these degree distributions
    for (int i = lo + 1; i < lo + d; i++) {
      int v = idx[i];
      int j = i - 1;
      while (j >= lo && idx[j] > v) { idx[j + 1] = idx[j]; j--; }
      idx[j + 1] = v;
    }
  }
}

// ---------------- neighbor mean ----------------
__global__ void agg_mean_kernel(const float* __restrict__ src, float* __restrict__ out,
                                const int* __restrict__ indptr, const int* __restrict__ idx,
                                int D) {
  int k = blockIdx.x * 256 + threadIdx.x;
  int d = blockIdx.y;
  int lo = indptr[d], hi = indptr[d + 1];
  float s = 0.f;
  for (int j = lo; j < hi; j++) s += src[(size_t)idx[j] * D + k];
  int c = hi - lo;
  out[(size_t)d * D + k] = s / (float)(c > 0 ? c : 1);
}

// ---------------- fp32 -> bf16 hi/lo split ----------------
__device__ inline unsigned short f2bf(float f) {
  unsigned int u = __float_as_uint(f);
  u += 0x7FFFu + ((u >> 16) & 1u); // RNE
  return (unsigned short)(u >> 16);
}
__device__ inline float bf2f(unsigned short h) {
  return __uint_as_float(((unsigned int)h) << 16);
}

__global__ void split_kernel(const float* __restrict__ src, unsigned short* __restrict__ dh,
                             unsigned short* __restrict__ dl, int n4) {
  int i = blockIdx.x * 256 + threadIdx.x;
  int stride = gridDim.x * 256;
  for (; i < n4; i += stride) {
    float4 v = ((const float4*)src)[i];
    ushort4 h, l;
    h.x = f2bf(v.x); l.x = f2bf(v.x - bf2f(h.x));
    h.y = f2bf(v.y); l.y = f2bf(v.y - bf2f(h.y));
    h.z = f2bf(v.z); l.z = f2bf(v.z - bf2f(h.z));
    h.w = f2bf(v.w); l.w = f2bf(v.w - bf2f(h.w));
    ((ushort4*)dh)[i] = h;
    ((ushort4*)dl)[i] = l;
  }
}

// ---------------- split-bf16 x3 MFMA NT GEMM ----------------
// C[m][n] (+)= sum_k A[m,k]*B[n,k], A=[4096][K] bf16 hi/lo, B=[1024][K] bf16 hi/lo.
// mode 0: C = raw partial. mode 1: C = leaky(C + acc + bias[row]).
// mode 2: C = leaky(C + acc + bias[col]).
// 512 threads = 8 waves (2/SIMD), 128x128 tile, wave sub-tile 32x64.
#define GBM 128
#define GBN 128
#define GBK 32

#define GLDS(g, l)                                                             \
  __builtin_amdgcn_global_load_lds(                                            \
      (const __attribute__((address_space(1))) void*)(g),                      \
      (__attribute__((address_space(3))) void*)(l), 16, 0, 0)

__global__ __launch_bounds__(512, 1) void split_gemm_kernel(
    const unsigned short* __restrict__ Ah, const unsigned short* __restrict__ Al,
    const unsigned short* __restrict__ Bh, const unsigned short* __restrict__ Bl,
    const float* __restrict__ bias, float* __restrict__ C, int K, int mode) {
  // 2 buffers x {Ah,Al,Bh,Bl} x [128][32] bf16 (8KB) = 64KB
  __shared__ unsigned short sm[2][4][GBM * GBK];
  const int tid = threadIdx.x;
  const int lane = tid & 63;
  const int wid = tid >> 6;           // 8 waves
  const int wr = wid >> 1, wc = wid & 1; // wave tile: rows wr*32..+32, cols wc*64..+64

  // XCD-chunked swizzle: 256 blocks; each XCD gets 4 consecutive m-panels x all n.
  const int bid = blockIdx.x;
  const int swz = (bid & 7) * 32 + (bid >> 3);
  const int bm0 = (swz >> 3) * GBM;
  const int bn0 = (swz & 7) * GBN;

  // staging: tile = 512 units of 16B; unit u -> LDS offset u*16 (linear, as
  // global_load_lds requires); global source k-slot = (u&3)^(row&3)
  // (pre-swizzled source; ds_read applies the same XOR -> involution).
  const int u = tid;
  const int r = u >> 2;
  const int c = ((u & 3) ^ (r & 3)) * 8;

  const unsigned short* gAh = Ah + (size_t)(bm0 + r) * K + c;
  const unsigned short* gAl = Al + (size_t)(bm0 + r) * K + c;
  const unsigned short* gBh = Bh + (size_t)(bn0 + r) * K + c;
  const unsigned short* gBl = Bl + (size_t)(bn0 + r) * K + c;

  // ds_read offsets (ushort units): frag row rr, k-slot s=lane>>4,
  // unit = rr*4 + (s ^ (rr&3))
  int offA[2], offB[4];
  {
    int s = lane >> 4;
#pragma unroll
    for (int i = 0; i < 2; i++) {
      int rA = wr * 32 + i * 16 + (lane & 15);
      offA[i] = rA * 32 + ((s ^ (rA & 3)) * 8);
    }
#pragma unroll
    for (int j = 0; j < 4; j++) {
      int rB = wc * 64 + j * 16 + (lane & 15);
      offB[j] = rB * 32 + ((s ^ (rB & 3)) * 8);
    }
  }

  f32x4 acc[2][4];
#pragma unroll
  for (int i = 0; i < 2; i++)
#pragma unroll
    for (int j = 0; j < 4; j++) acc[i][j] = (f32x4)(0.f);

#define STAGE(buf)                                                             \
  {                                                                            \
    GLDS(gAh, &sm[buf][0][u * 8]);                                             \
    GLDS(gAl, &sm[buf][1][u * 8]);                                             \
    GLDS(gBh, &sm[buf][2][u * 8]);                                             \
    GLDS(gBl, &sm[buf][3][u * 8]);                                             \
    gAh += GBK; gAl += GBK; gBh += GBK; gBl += GBK;                            \
  }

  const int nt = K / GBK;
  STAGE(0);
  int cur = 0;
  for (int t = 0; t < nt; t++) {
    __syncthreads(); // drains vmcnt -> sm[cur] staged; prior reads of sm[cur^1] done
    if (t + 1 < nt) STAGE(cur ^ 1); // prefetch next tile; drained at next barrier
    short8 fah[2], fal[2], fbh[4], fbl[4];
#pragma unroll
    for (int i = 0; i < 2; i++) {
      fah[i] = *(const short8*)&sm[cur][0][offA[i]];
      fal[i] = *(const short8*)&sm[cur][1][offA[i]];
    }
#pragma unroll
    for (int j = 0; j < 4; j++) {
      fbh[j] = *(const short8*)&sm[cur][2][offB[j]];
      fbl[j] = *(const short8*)&sm[cur][3][offB[j]];
    }
    // three sweeps (hh, hl, lh): 7 independent MFMAs between reuses of one acc
#pragma unroll
    for (int i = 0; i < 2; i++)
#pragma unroll
      for (int j = 0; j < 4; j++)
        acc[i][j] = __builtin_amdgcn_mfma_f32_16x16x32_bf16(fah[i], fbh[j], acc[i][j], 0, 0, 0);
#pragma unroll
    for (int i = 0; i < 2; i++)
#pragma unroll
      for (int j = 0; j < 4; j++)
        acc[i][j] = __builtin_amdgcn_mfma_f32_16x16x32_bf16(fah[i], fbl[j], acc[i][j], 0, 0, 0);
#pragma unroll
    for (int i = 0; i < 2; i++)
#pragma unroll
      for (int j = 0; j < 4; j++)
        acc[i][j] = __builtin_amdgcn_mfma_f32_16x16x32_bf16(fal[i], fbh[j], acc[i][j], 0, 0, 0);
    cur ^= 1;
  }

  const int rowq = (lane >> 4) * 4;
  const int colq = lane & 15;
#pragma unroll
  for (int i = 0; i < 2; i++) {
#pragma unroll
    for (int j = 0; j < 4; j++) {
#pragma unroll
      for (int q = 0; q < 4; q++) {
        int row = bm0 + wr * 32 + i * 16 + rowq + q;
        int col = bn0 + wc * 64 + j * 16 + colq;
        size_t o = (size_t)row * 1024 + col;
        float v = acc[i][j][q];
        if (mode == 0) {
          C[o] = v;
        } else {
          float x = C[o] + v + (mode == 1 ? bias[row] : bias[col]);
          C[o] = x > 0.f ? x : 0.01f * x;
        }
      }
    }
  }
}

extern "C" void kernel_launch(void* const* d_in, const int* in_sizes, int n_in,
                              void* d_out, int out_size, void* d_ws, size_t ws_size,
                              hipStream_t stream) {
  const float* x      = (const float*)d_in[0];
  const float* col_Wl = (const float*)d_in[1];
  const float* col_Wr = (const float*)d_in[2];
  const float* col_b  = (const float*)d_in[3];
  const float* row_Wl = (const float*)d_in[4];
  const float* row_Wr = (const float*)d_in[5];
  const float* row_b  = (const float*)d_in[6];
  const int*   knn    = (const int*)d_in[7];   // [2][KNN_E]
  const int*   genet  = (const int*)d_in[8];   // [2][GENET_E]
  float* out = (float*)d_out;

  const size_t MAT = (size_t)COL_DIM * ROW_DIM; // 4M floats
  char* w = (char*)d_ws;
  float* ET   = (float*)w; w += MAT * 4;              // [1024][4096] fp32
  float* MEAN = (float*)w; w += MAT * 4;              // [1024][4096] or [4096][1024]
  float* E1   = (float*)w; w += MAT * 4;              // [4096][1024] fp32
  unsigned short* SAh = (unsigned short*)w; w += (size_t)COL_DIM * COL_DIM * 2; // 32MB
  unsigned short* SAl = (unsigned short*)w; w += (size_t)COL_DIM * COL_DIM * 2; // 32MB
  unsigned short* SBh = (unsigned short*)w; w += (size_t)ROW_DIM * COL_DIM * 2; // 8MB
  unsigned short* SBl = (unsigned short*)w; w += (size_t)ROW_DIM * COL_DIM * 2; // 8MB
  int* kcnt = (int*)w; w += 1024 * 4;
  int* kptr = (int*)w; w += 1025 * 4;
  int* kidx = (int*)w; w += KNN_E * 4;
  int* gcnt = (int*)w; w += 4096 * 4;
  int* gptr = (int*)w; w += 4097 * 4;
  int* gidx = (int*)w; w += (size_t)GENET_E * 4;

  // ---- CSR build (deterministic via per-bucket value sort) ----
  hipMemsetAsync(kcnt, 0, 1024 * 4, stream);
  hipMemsetAsync(gcnt, 0, 4096 * 4, stream);
  count_kernel<<<KNN_E / 256, 256, 0, stream>>>(knn + KNN_E, KNN_E, kcnt);
  count_kernel<<<GENET_E / 256, 256, 0, stream>>>(genet + GENET_E, GENET_E, gcnt);
  scan_kernel<<<1, 1024, 0, stream>>>(kcnt, kptr, 1024);
  scan_kernel<<<1, 1024, 0, stream>>>(gcnt, gptr, 4096);
  copy_int_kernel<<<4, 256, 0, stream>>>(kptr, kcnt, 1024);
  copy_int_kernel<<<16, 256, 0, stream>>>(gptr, gcnt, 4096);
  fill_kernel<<<KNN_E / 256, 256, 0, stream>>>(knn, knn + KNN_E, KNN_E, kcnt, kidx);
  fill_kernel<<<GENET_E / 256, 256, 0, stream>>>(genet, genet + GENET_E, GENET_E, gcnt, gidx);
  rank_sort_kernel<<<256, 256, 0, stream>>>(kptr, kidx, 1024);
  rank_sort_kernel<<<1024, 256, 0, stream>>>(gptr, gidx, 4096);

  const float* Ein = x;
  for (int i = 0; i < NUM_LAYERS; i++) {
    const float* cWl = col_Wl + (size_t)i * COL_DIM * COL_DIM;
    const float* cWr = col_Wr + (size_t)i * COL_DIM * COL_DIM;
    const float* cb  = col_b + (size_t)i * COL_DIM;
    const float* rWl = row_Wl + (size_t)i * ROW_DIM * ROW_DIM;
    const float* rWr = row_Wr + (size_t)i * ROW_DIM * ROW_DIM;
    const float* rb  = row_b + (size_t)i * ROW_DIM;

    // ---- column branch: E1 = leaky(Wl@mean_c^T + Wr@Ein + cb[m]) ----
    transpose_kernel<<<dim3(ROW_DIM / 32, COL_DIM / 32), dim3(32, 8), 0, stream>>>(
        Ein, ET, COL_DIM, ROW_DIM);
    agg_mean_kernel<<<dim3(COL_DIM / 256, ROW_DIM), 256, 0, stream>>>(
        ET, MEAN, kptr, kidx, COL_DIM);
    split_kernel<<<2048, 256, 0, stream>>>(MEAN, SBh, SBl, (int)(MAT / 4));
    split_kernel<<<2048, 256, 0, stream>>>(cWl, SAh, SAl, COL_DIM * COL_DIM / 4);
    split_gemm_kernel<<<256, 512, 0, stream>>>(SAh, SAl, SBh, SBl, cb, E1, COL_DIM, 0);
    split_kernel<<<2048, 256, 0, stream>>>(ET, SBh, SBl, (int)(MAT / 4));
    split_kernel<<<2048, 256, 0, stream>>>(cWr, SAh, SAl, COL_DIM * COL_DIM / 4);
    split_gemm_kernel<<<256, 512, 0, stream>>>(SAh, SAl, SBh, SBl, cb, E1, COL_DIM, 1);

    // ---- row branch: out = leaky(mean_g@rWl^T + E1@rWr^T + rb[n]) ----
    agg_mean_kernel<<<dim3(ROW_DIM / 256, COL_DIM), 256, 0, stream>>>(
        E1, MEAN, gptr, gidx, ROW_DIM);
    split_kernel<<<2048, 256, 0, stream>>>(MEAN, SAh, SAl, (int)(MAT / 4));
    split_kernel<<<1024, 256, 0, stream>>>(rWl, SBh, SBl, ROW_DIM * ROW_DIM / 4);
    split_gemm_kernel<<<256, 512, 0, stream>>>(SAh, SAl, SBh, SBl, rb, out, ROW_DIM, 0);
    split_kernel<<<2048, 256, 0, stream>>>(E1, SAh, SAl, (int)(MAT / 4));
    split_kernel<<<1024, 256, 0, stream>>>(rWr, SBh, SBl, ROW_DIM * ROW_DIM / 4);
    split_gemm_kernel<<<256, 512, 0, stream>>>(SAh, SAl, SBh, SBl, rb, out, ROW_DIM, 2);

    Ein = out;
  }
}

// Round 4
// 1327.839 us; speedup vs baseline: 3.1531x; 1.1367x over previous
//
#include <hip/hip_runtime.h>

#define COL_DIM 4096
#define ROW_DIM 1024
#define NUM_LAYERS 3
#define KNN_E 16384
#define GENET_E 131072

typedef __attribute__((ext_vector_type(8))) short short8;
typedef __attribute__((ext_vector_type(4))) float f32x4;

// ---------------- transpose: in[R][C] -> out[C][R] ----------------
__global__ void transpose_kernel(const float* __restrict__ in, float* __restrict__ out,
                                 int R, int C) {
  __shared__ float tile[32][33];
  int c0 = blockIdx.x * 32, r0 = blockIdx.y * 32;
  int tx = threadIdx.x, ty = threadIdx.y; // 32 x 8
#pragma unroll
  for (int i = 0; i < 32; i += 8)
    tile[ty + i][tx] = in[(size_t)(r0 + ty + i) * C + c0 + tx];
  __syncthreads();
#pragma unroll
  for (int i = 0; i < 32; i += 8)
    out[(size_t)(c0 + ty + i) * R + r0 + tx] = tile[tx][ty + i];
}

// ---------------- CSR build ----------------
__global__ void count_kernel(const int* __restrict__ dst, int E, int* __restrict__ cnt) {
  int e = blockIdx.x * 256 + threadIdx.x;
  if (e < E) atomicAdd(&cnt[dst[e]], 1);
}

__global__ void scan_kernel(const int* __restrict__ cnt, int* __restrict__ indptr, int n) {
  __shared__ int s[1024];
  __shared__ int base_s;
  int tid = threadIdx.x;
  if (tid == 0) { base_s = 0; indptr[0] = 0; }
  __syncthreads();
  for (int c = 0; c < n; c += 1024) {
    int i = c + tid;
    int v = (i < n) ? cnt[i] : 0;
    s[tid] = v;
    __syncthreads();
    for (int off = 1; off < 1024; off <<= 1) {
      int t = (tid >= off) ? s[tid - off] : 0;
      __syncthreads();
      s[tid] += t;
      __syncthreads();
    }
    if (i < n) indptr[i + 1] = base_s + s[tid];
    __syncthreads();
    if (tid == 0) base_s += s[1023];
    __syncthreads();
  }
}

__global__ void copy_int_kernel(const int* __restrict__ a, int* __restrict__ b, int n) {
  int i = blockIdx.x * 256 + threadIdx.x;
  if (i < n) b[i] = a[i];
}

__global__ void fill_kernel(const int* __restrict__ src, const int* __restrict__ dst, int E,
                            int* __restrict__ cursor, int* __restrict__ idx) {
  int e = blockIdx.x * 256 + threadIdx.x;
  if (e < E) {
    int p = atomicAdd(&cursor[dst[e]], 1);
    idx[p] = src[e];
  }
}

// ---------------- wave-per-bucket rank sort (deterministic: sorted by value) ---
__global__ void rank_sort_kernel(const int* __restrict__ indptr, int* __restrict__ idx,
                                 int n) {
  int wv = threadIdx.x >> 6, lane = threadIdx.x & 63;
  int b = blockIdx.x * (blockDim.x >> 6) + wv;
  if (b >= n) return;
  int lo = indptr[b];
  int d = indptr[b + 1] - lo;
  if (d <= 1) return;
  if (d <= 256) {
    int v0 = (lane < d) ? idx[lo + lane] : 0x7fffffff;
    int v1 = (64 + lane < d) ? idx[lo + 64 + lane] : 0x7fffffff;
    int v2 = (128 + lane < d) ? idx[lo + 128 + lane] : 0x7fffffff;
    int v3 = (192 + lane < d) ? idx[lo + 192 + lane] : 0x7fffffff;
    int r0 = 0, r1 = 0, r2 = 0, r3 = 0;
    for (int j = 0; j < d; j++) {
      int q = j >> 6;
      int sel = (q == 0) ? v0 : (q == 1) ? v1 : (q == 2) ? v2 : v3;
      int bj = __shfl(sel, j & 63);
      r0 += (bj < v0 || (bj == v0 && j < lane)) ? 1 : 0;
      r1 += (bj < v1 || (bj == v1 && j < 64 + lane)) ? 1 : 0;
      r2 += (bj < v2 || (bj == v2 && j < 128 + lane)) ? 1 : 0;
      r3 += (bj < v3 || (bj == v3 && j < 192 + lane)) ? 1 : 0;
    }
    if (lane < d) idx[lo + r0] = v0;
    if (64 + lane < d) idx[lo + r1] = v1;
    if (128 + lane < d) idx[lo + r2] = v2;
    if (192 + lane < d) idx[lo + r3] = v3;
  } else if (lane == 0) {
    for (int i = lo + 1; i < lo + d; i++) {
      int v = idx[i];
      int j = i - 1;
      while (j >= lo && idx[j] > v) { idx[j + 1] = idx[j]; j--; }
      idx[j + 1] = v;
    }
  }
}

// ---------------- neighbor mean (float4) ----------------
__global__ void agg_mean4_kernel(const float* __restrict__ src, float* __restrict__ out,
                                 const int* __restrict__ indptr, const int* __restrict__ idx,
                                 int D) {
  int k4 = blockIdx.x * 256 + threadIdx.x; // float4 column index
  int d = blockIdx.y;
  int lo = indptr[d], hi = indptr[d + 1];
  float4 s = make_float4(0.f, 0.f, 0.f, 0.f);
  for (int j = lo; j < hi; j++) {
    float4 v = ((const float4*)(src + (size_t)idx[j] * D))[k4];
    s.x += v.x; s.y += v.y; s.z += v.z; s.w += v.w;
  }
  int c = hi - lo;
  float inv = 1.f / (float)(c > 0 ? c : 1);
  s.x *= inv; s.y *= inv; s.z *= inv; s.w *= inv;
  ((float4*)(out + (size_t)d * D))[k4] = s;
}

// ---------------- fp32 -> bf16 hi/lo split ----------------
__device__ inline unsigned short f2bf(float f) {
  unsigned int u = __float_as_uint(f);
  u += 0x7FFFu + ((u >> 16) & 1u); // RNE
  return (unsigned short)(u >> 16);
}
__device__ inline float bf2f(unsigned short h) {
  return __uint_as_float(((unsigned int)h) << 16);
}

__global__ void split_kernel(const float* __restrict__ src, unsigned short* __restrict__ dh,
                             unsigned short* __restrict__ dl, int n4) {
  int i = blockIdx.x * 256 + threadIdx.x;
  int stride = gridDim.x * 256;
  for (; i < n4; i += stride) {
    float4 v = ((const float4*)src)[i];
    ushort4 h, l;
    h.x = f2bf(v.x); l.x = f2bf(v.x - bf2f(h.x));
    h.y = f2bf(v.y); l.y = f2bf(v.y - bf2f(h.y));
    h.z = f2bf(v.z); l.z = f2bf(v.z - bf2f(h.z));
    h.w = f2bf(v.w); l.w = f2bf(v.w - bf2f(h.w));
    ((ushort4*)dh)[i] = h;
    ((ushort4*)dl)[i] = l;
  }
}

// ---------------- split-bf16 x3 MFMA NT GEMM (partial, split-K=2) ----------------
// P[m][n] = sum_{k in half} A[m,k]*B[n,k] (3-sweep split-bf16).
// Grid 512: bid&255 = output tile (128x128), bid>>8 = K-half.
// 256 threads = 4 waves, wave tile 64x64 -> 16 ds_read_b128 : 48 MFMA per K-step.
#define GBM 128
#define GBN 128
#define GBK 32

#define GLDS(g, l)                                                             \
  __builtin_amdgcn_global_load_lds(                                            \
      (const __attribute__((address_space(1))) void*)(g),                      \
      (__attribute__((address_space(3))) void*)(l), 16, 0, 0)

__global__ __launch_bounds__(256, 2) void split_gemm_kernel(
    const unsigned short* __restrict__ Ah, const unsigned short* __restrict__ Al,
    const unsigned short* __restrict__ Bh, const unsigned short* __restrict__ Bl,
    float* __restrict__ P0, float* __restrict__ P1, int Ktot, int Kblk) {
  // 2 buffers x {Ah,Al,Bh,Bl} x [128][32] bf16 (8KB) = 64KB
  __shared__ unsigned short sm[2][4][GBM * GBK];
  const int tid = threadIdx.x;
  const int lane = tid & 63;
  const int wid = tid >> 6;               // 4 waves
  const int wr = wid >> 1, wc = wid & 1;  // wave tile: rows wr*64.., cols wc*64..

  const int bid = blockIdx.x;
  const int kh = bid >> 8;
  const int tile = bid & 255;
  // XCD-chunked swizzle over the 256 output tiles
  const int swz = (tile & 7) * 32 + (tile >> 3);
  const int bm0 = (swz >> 3) * GBM;
  const int bn0 = (swz & 7) * GBN;
  const size_t kbase = (size_t)kh * Kblk;

  // staging: per operand 512 units of 16B; unit u -> LDS offset u*16 (linear).
  // global source k-slot = (u&3) ^ ((r>>1)&3)  [conflict-free involution]
  const int u0 = tid, u1 = tid + 256;
  const int r0 = u0 >> 2, r1 = u1 >> 2;
  const int c0 = ((u0 & 3) ^ ((r0 >> 1) & 3)) * 8;
  const int c1 = ((u1 & 3) ^ ((r1 >> 1) & 3)) * 8;

  const unsigned short* gAh0 = Ah + (size_t)(bm0 + r0) * Ktot + kbase + c0;
  const unsigned short* gAh1 = Ah + (size_t)(bm0 + r1) * Ktot + kbase + c1;
  const unsigned short* gAl0 = Al + (size_t)(bm0 + r0) * Ktot + kbase + c0;
  const unsigned short* gAl1 = Al + (size_t)(bm0 + r1) * Ktot + kbase + c1;
  const unsigned short* gBh0 = Bh + (size_t)(bn0 + r0) * Ktot + kbase + c0;
  const unsigned short* gBh1 = Bh + (size_t)(bn0 + r1) * Ktot + kbase + c1;
  const unsigned short* gBl0 = Bl + (size_t)(bn0 + r0) * Ktot + kbase + c0;
  const unsigned short* gBl1 = Bl + (size_t)(bn0 + r1) * Ktot + kbase + c1;

  // ds_read offsets (ushort units): frag row rr, logical k-slot s=lane>>4,
  // physical slot = s ^ ((rr>>1)&3)
  int offA[4], offB[4];
  {
    int s = lane >> 4;
#pragma unroll
    for (int i = 0; i < 4; i++) {
      int rA = wr * 64 + i * 16 + (lane & 15);
      offA[i] = rA * 32 + ((s ^ ((rA >> 1) & 3)) * 8);
      int rB = wc * 64 + i * 16 + (lane & 15);
      offB[i] = rB * 32 + ((s ^ ((rB >> 1) & 3)) * 8);
    }
  }

  f32x4 acc[4][4];
#pragma unroll
  for (int i = 0; i < 4; i++)
#pragma unroll
    for (int j = 0; j < 4; j++) acc[i][j] = (f32x4)(0.f);

#define STAGE(buf)                                                             \
  {                                                                            \
    GLDS(gAh0, &sm[buf][0][u0 * 8]); GLDS(gAh1, &sm[buf][0][u1 * 8]);          \
    GLDS(gAl0, &sm[buf][1][u0 * 8]); GLDS(gAl1, &sm[buf][1][u1 * 8]);          \
    GLDS(gBh0, &sm[buf][2][u0 * 8]); GLDS(gBh1, &sm[buf][2][u1 * 8]);          \
    GLDS(gBl0, &sm[buf][3][u0 * 8]); GLDS(gBl1, &sm[buf][3][u1 * 8]);          \
    gAh0 += GBK; gAh1 += GBK; gAl0 += GBK; gAl1 += GBK;                        \
    gBh0 += GBK; gBh1 += GBK; gBl0 += GBK; gBl1 += GBK;                        \
  }

  const int nt = Kblk / GBK;
  STAGE(0);
  int cur = 0;
  for (int t = 0; t < nt; t++) {
    __syncthreads(); // drains vmcnt -> sm[cur] staged; prior reads of sm[cur^1] done
    if (t + 1 < nt) STAGE(cur ^ 1);
    short8 fah[4], fal[4], fbh[4], fbl[4];
#pragma unroll
    for (int i = 0; i < 4; i++) {
      fah[i] = *(const short8*)&sm[cur][0][offA[i]];
      fal[i] = *(const short8*)&sm[cur][1][offA[i]];
      fbh[i] = *(const short8*)&sm[cur][2][offB[i]];
      fbl[i] = *(const short8*)&sm[cur][3][offB[i]];
    }
    // three sweeps (hh, hl, lh): 15 independent MFMAs between reuses of one acc
#pragma unroll
    for (int i = 0; i < 4; i++)
#pragma unroll
      for (int j = 0; j < 4; j++)
        acc[i][j] = __builtin_amdgcn_mfma_f32_16x16x32_bf16(fah[i], fbh[j], acc[i][j], 0, 0, 0);
#pragma unroll
    for (int i = 0; i < 4; i++)
#pragma unroll
      for (int j = 0; j < 4; j++)
        acc[i][j] = __builtin_amdgcn_mfma_f32_16x16x32_bf16(fah[i], fbl[j], acc[i][j], 0, 0, 0);
#pragma unroll
    for (int i = 0; i < 4; i++)
#pragma unroll
      for (int j = 0; j < 4; j++)
        acc[i][j] = __builtin_amdgcn_mfma_f32_16x16x32_bf16(fal[i], fbh[j], acc[i][j], 0, 0, 0);
    cur ^= 1;
  }

  float* P = kh ? P1 : P0;
  const int rowq = (lane >> 4) * 4;
  const int colq = lane & 15;
#pragma unroll
  for (int i = 0; i < 4; i++) {
#pragma unroll
    for (int j = 0; j < 4; j++) {
#pragma unroll
      for (int q = 0; q < 4; q++) {
        int row = bm0 + wr * 64 + i * 16 + rowq + q;
        int col = bn0 + wc * 64 + j * 16 + colq;
        P[(size_t)row * 1024 + col] = acc[i][j][q];
      }
    }
  }
}

// ---------------- combine: C = leaky(P0+P1+P2+P3 + bias) ----------------
// biasPerRow=1 -> bias[row] (row = idx/1024); else bias[col] (col = idx%1024)
__global__ void combine_kernel(const float* __restrict__ P0, const float* __restrict__ P1,
                               const float* __restrict__ P2, const float* __restrict__ P3,
                               const float* __restrict__ bias, float* __restrict__ C,
                               int biasPerRow) {
  int i = blockIdx.x * 256 + threadIdx.x; // float4 index, 1M total
  float4 a = ((const float4*)P0)[i];
  float4 b = ((const float4*)P1)[i];
  float4 c = ((const float4*)P2)[i];
  float4 d = ((const float4*)P3)[i];
  int base = i * 4;
  float4 v;
  if (biasPerRow) {
    float bb = bias[base >> 10];
    v.x = a.x + b.x + c.x + d.x + bb;
    v.y = a.y + b.y + c.y + d.y + bb;
    v.z = a.z + b.z + c.z + d.z + bb;
    v.w = a.w + b.w + c.w + d.w + bb;
  } else {
    float4 bb = *(const float4*)(bias + (base & 1023));
    v.x = a.x + b.x + c.x + d.x + bb.x;
    v.y = a.y + b.y + c.y + d.y + bb.y;
    v.z = a.z + b.z + c.z + d.z + bb.z;
    v.w = a.w + b.w + c.w + d.w + bb.w;
  }
  v.x = v.x > 0.f ? v.x : 0.01f * v.x;
  v.y = v.y > 0.f ? v.y : 0.01f * v.y;
  v.z = v.z > 0.f ? v.z : 0.01f * v.z;
  v.w = v.w > 0.f ? v.w : 0.01f * v.w;
  ((float4*)C)[i] = v;
}

extern "C" void kernel_launch(void* const* d_in, const int* in_sizes, int n_in,
                              void* d_out, int out_size, void* d_ws, size_t ws_size,
                              hipStream_t stream) {
  const float* x      = (const float*)d_in[0];
  const float* col_Wl = (const float*)d_in[1];
  const float* col_Wr = (const float*)d_in[2];
  const float* col_b  = (const float*)d_in[3];
  const float* row_Wl = (const float*)d_in[4];
  const float* row_Wr = (const float*)d_in[5];
  const float* row_b  = (const float*)d_in[6];
  const int*   knn    = (const int*)d_in[7];   // [2][KNN_E]
  const int*   genet  = (const int*)d_in[8];   // [2][GENET_E]
  float* out = (float*)d_out;

  const size_t MAT = (size_t)COL_DIM * ROW_DIM; // 4M floats
  char* w = (char*)d_ws;
  float* ET   = (float*)w; w += MAT * 4;   // 16MB — also P2 (dead after its split)
  float* MEAN = (float*)w; w += MAT * 4;   // 16MB — also P0 (dead after its split)
  float* E1   = (float*)w; w += MAT * 4;   // 16MB
  float* PX1  = (float*)w; w += MAT * 4;   // 16MB dedicated partial
  float* PX3  = (float*)w; w += MAT * 4;   // 16MB dedicated partial
  unsigned short* SAh = (unsigned short*)w; w += (size_t)COL_DIM * COL_DIM * 2; // 32MB
  unsigned short* SAl = (unsigned short*)w; w += (size_t)COL_DIM * COL_DIM * 2; // 32MB
  unsigned short* SBh = (unsigned short*)w; w += (size_t)ROW_DIM * COL_DIM * 2; // 8MB
  unsigned short* SBl = (unsigned short*)w; w += (size_t)ROW_DIM * COL_DIM * 2; // 8MB
  int* kcnt = (int*)w; w += 1024 * 4;
  int* kptr = (int*)w; w += 1025 * 4;
  int* kidx = (int*)w; w += KNN_E * 4;
  int* gcnt = (int*)w; w += 4096 * 4;
  int* gptr = (int*)w; w += 4097 * 4;
  int* gidx = (int*)w; w += (size_t)GENET_E * 4;

  float* P0 = MEAN; // aliases: dead (already split to bf16) when GEMM writes them
  float* P2 = ET;

  // ---- CSR build (deterministic via per-bucket value sort) ----
  hipMemsetAsync(kcnt, 0, 1024 * 4, stream);
  hipMemsetAsync(gcnt, 0, 4096 * 4, stream);
  count_kernel<<<KNN_E / 256, 256, 0, stream>>>(knn + KNN_E, KNN_E, kcnt);
  count_kernel<<<GENET_E / 256, 256, 0, stream>>>(genet + GENET_E, GENET_E, gcnt);
  scan_kernel<<<1, 1024, 0, stream>>>(kcnt, kptr, 1024);
  scan_kernel<<<1, 1024, 0, stream>>>(gcnt, gptr, 4096);
  copy_int_kernel<<<4, 256, 0, stream>>>(kptr, kcnt, 1024);
  copy_int_kernel<<<16, 256, 0, stream>>>(gptr, gcnt, 4096);
  fill_kernel<<<KNN_E / 256, 256, 0, stream>>>(knn, knn + KNN_E, KNN_E, kcnt, kidx);
  fill_kernel<<<GENET_E / 256, 256, 0, stream>>>(genet, genet + GENET_E, GENET_E, gcnt, gidx);
  rank_sort_kernel<<<256, 256, 0, stream>>>(kptr, kidx, 1024);
  rank_sort_kernel<<<1024, 256, 0, stream>>>(gptr, gidx, 4096);

  const float* Ein = x;
  for (int i = 0; i < NUM_LAYERS; i++) {
    const float* cWl = col_Wl + (size_t)i * COL_DIM * COL_DIM;
    const float* cWr = col_Wr + (size_t)i * COL_DIM * COL_DIM;
    const float* cb  = col_b + (size_t)i * COL_DIM;
    const float* rWl = row_Wl + (size_t)i * ROW_DIM * ROW_DIM;
    const float* rWr = row_Wr + (size_t)i * ROW_DIM * ROW_DIM;
    const float* rb  = row_b + (size_t)i * ROW_DIM;

    // ---- column branch: E1 = leaky(Wl@mean_c^T + Wr@Ein^T^T ... + cb[row]) ----
    transpose_kernel<<<dim3(ROW_DIM / 32, COL_DIM / 32), dim3(32, 8), 0, stream>>>(
        Ein, ET, COL_DIM, ROW_DIM);
    agg_mean4_kernel<<<dim3(COL_DIM / 1024, ROW_DIM), 256, 0, stream>>>(
        ET, MEAN, kptr, kidx, COL_DIM);
    split_kernel<<<2048, 256, 0, stream>>>(MEAN, SBh, SBl, (int)(MAT / 4));   // MEAN dead
    split_kernel<<<2048, 256, 0, stream>>>(cWl, SAh, SAl, COL_DIM * COL_DIM / 4);
    split_gemm_kernel<<<512, 256, 0, stream>>>(SAh, SAl, SBh, SBl, P0, PX1,
                                               COL_DIM, COL_DIM / 2);
    split_kernel<<<2048, 256, 0, stream>>>(ET, SBh, SBl, (int)(MAT / 4));     // ET dead
    split_kernel<<<2048, 256, 0, stream>>>(cWr, SAh, SAl, COL_DIM * COL_DIM / 4);
    split_gemm_kernel<<<512, 256, 0, stream>>>(SAh, SAl, SBh, SBl, P2, PX3,
                                               COL_DIM, COL_DIM / 2);
    combine_kernel<<<4096, 256, 0, stream>>>(P0, PX1, P2, PX3, cb, E1, 1);

    // ---- row branch: out = leaky(mean_g@rWl^T + E1@rWr^T + rb[col]) ----
    agg_mean4_kernel<<<dim3(ROW_DIM / 1024, COL_DIM), 256, 0, stream>>>(
        E1, MEAN, gptr, gidx, ROW_DIM);
    split_kernel<<<2048, 256, 0, stream>>>(MEAN, SAh, SAl, (int)(MAT / 4));   // MEAN dead
    split_kernel<<<1024, 256, 0, stream>>>(rWl, SBh, SBl, ROW_DIM * ROW_DIM / 4);
    split_gemm_kernel<<<512, 256, 0, stream>>>(SAh, SAl, SBh, SBl, P0, PX1,
                                               ROW_DIM, ROW_DIM / 2);
    split_kernel<<<2048, 256, 0, stream>>>(E1, SAh, SAl, (int)(MAT / 4));     // E1 dead
    split_kernel<<<1024, 256, 0, stream>>>(rWr, SBh, SBl, ROW_DIM * ROW_DIM / 4);
    split_gemm_kernel<<<512, 256, 0, stream>>>(SAh, SAl, SBh, SBl, P2, PX3,
                                               ROW_DIM, ROW_DIM / 2);
    combine_kernel<<<4096, 256, 0, stream>>>(P0, PX1, P2, PX3, rb, out, 0);

    Ein = out;
  }
}

// Round 5
// 1318.756 us; speedup vs baseline: 3.1748x; 1.0069x over previous
//
#include <hip/hip_runtime.h>

#define COL_DIM 4096
#define ROW_DIM 1024
#define NUM_LAYERS 3
#define KNN_E 16384
#define GENET_E 131072

typedef __attribute__((ext_vector_type(8))) short short8;
typedef __attribute__((ext_vector_type(4))) float f32x4;

// ---------------- fp32 -> bf16 hi/lo helpers ----------------
__device__ inline unsigned short f2bf(float f) {
  unsigned int u = __float_as_uint(f);
  u += 0x7FFFu + ((u >> 16) & 1u); // RNE
  return (unsigned short)(u >> 16);
}
__device__ inline float bf2f(unsigned short h) {
  return __uint_as_float(((unsigned int)h) << 16);
}

// ---------------- transpose + split: in[R][C] -> outf/outh/outl [C][R] --------
__global__ void transpose_split_kernel(const float* __restrict__ in,
                                       float* __restrict__ outf,
                                       unsigned short* __restrict__ outh,
                                       unsigned short* __restrict__ outl,
                                       int R, int C) {
  __shared__ float tile[32][33];
  int c0 = blockIdx.x * 32, r0 = blockIdx.y * 32;
  int tx = threadIdx.x, ty = threadIdx.y; // 32 x 8
#pragma unroll
  for (int i = 0; i < 32; i += 8)
    tile[ty + i][tx] = in[(size_t)(r0 + ty + i) * C + c0 + tx];
  __syncthreads();
#pragma unroll
  for (int i = 0; i < 32; i += 8) {
    float v = tile[tx][ty + i];
    size_t o = (size_t)(c0 + ty + i) * R + r0 + tx;
    outf[o] = v;
    unsigned short h = f2bf(v);
    outh[o] = h;
    outl[o] = f2bf(v - bf2f(h));
  }
}

// ---------------- CSR build ----------------
__global__ void count_kernel(const int* __restrict__ dst, int E, int* __restrict__ cnt) {
  int e = blockIdx.x * 256 + threadIdx.x;
  if (e < E) atomicAdd(&cnt[dst[e]], 1);
}

__global__ void scan_kernel(const int* __restrict__ cnt, int* __restrict__ indptr, int n) {
  __shared__ int s[1024];
  __shared__ int base_s;
  int tid = threadIdx.x;
  if (tid == 0) { base_s = 0; indptr[0] = 0; }
  __syncthreads();
  for (int c = 0; c < n; c += 1024) {
    int i = c + tid;
    int v = (i < n) ? cnt[i] : 0;
    s[tid] = v;
    __syncthreads();
    for (int off = 1; off < 1024; off <<= 1) {
      int t = (tid >= off) ? s[tid - off] : 0;
      __syncthreads();
      s[tid] += t;
      __syncthreads();
    }
    if (i < n) indptr[i + 1] = base_s + s[tid];
    __syncthreads();
    if (tid == 0) base_s += s[1023];
    __syncthreads();
  }
}

__global__ void copy_int_kernel(const int* __restrict__ a, int* __restrict__ b, int n) {
  int i = blockIdx.x * 256 + threadIdx.x;
  if (i < n) b[i] = a[i];
}

__global__ void fill_kernel(const int* __restrict__ src, const int* __restrict__ dst, int E,
                            int* __restrict__ cursor, int* __restrict__ idx) {
  int e = blockIdx.x * 256 + threadIdx.x;
  if (e < E) {
    int p = atomicAdd(&cursor[dst[e]], 1);
    idx[p] = src[e];
  }
}

// ---------------- wave-per-bucket rank sort (deterministic: sorted by value) ---
__global__ void rank_sort_kernel(const int* __restrict__ indptr, int* __restrict__ idx,
                                 int n) {
  int wv = threadIdx.x >> 6, lane = threadIdx.x & 63;
  int b = blockIdx.x * (blockDim.x >> 6) + wv;
  if (b >= n) return;
  int lo = indptr[b];
  int d = indptr[b + 1] - lo;
  if (d <= 1) return;
  if (d <= 256) {
    int v0 = (lane < d) ? idx[lo + lane] : 0x7fffffff;
    int v1 = (64 + lane < d) ? idx[lo + 64 + lane] : 0x7fffffff;
    int v2 = (128 + lane < d) ? idx[lo + 128 + lane] : 0x7fffffff;
    int v3 = (192 + lane < d) ? idx[lo + 192 + lane] : 0x7fffffff;
    int r0 = 0, r1 = 0, r2 = 0, r3 = 0;
    for (int j = 0; j < d; j++) {
      int q = j >> 6;
      int sel = (q == 0) ? v0 : (q == 1) ? v1 : (q == 2) ? v2 : v3;
      int bj = __shfl(sel, j & 63);
      r0 += (bj < v0 || (bj == v0 && j < lane)) ? 1 : 0;
      r1 += (bj < v1 || (bj == v1 && j < 64 + lane)) ? 1 : 0;
      r2 += (bj < v2 || (bj == v2 && j < 128 + lane)) ? 1 : 0;
      r3 += (bj < v3 || (bj == v3 && j < 192 + lane)) ? 1 : 0;
    }
    if (lane < d) idx[lo + r0] = v0;
    if (64 + lane < d) idx[lo + r1] = v1;
    if (128 + lane < d) idx[lo + r2] = v2;
    if (192 + lane < d) idx[lo + r3] = v3;
  } else if (lane == 0) {
    for (int i = lo + 1; i < lo + d; i++) {
      int v = idx[i];
      int j = i - 1;
      while (j >= lo && idx[j] > v) { idx[j + 1] = idx[j]; j--; }
      idx[j + 1] = v;
    }
  }
}

// ---------------- neighbor mean (float4) + split to bf16 hi/lo ----------------
__global__ void agg_mean_split_kernel(const float* __restrict__ src,
                                      unsigned short* __restrict__ dh,
                                      unsigned short* __restrict__ dl,
                                      const int* __restrict__ indptr,
                                      const int* __restrict__ idx, int D) {
  int k4 = blockIdx.x * 256 + threadIdx.x; // float4 column index
  int d = blockIdx.y;
  int lo = indptr[d], hi = indptr[d + 1];
  float4 s = make_float4(0.f, 0.f, 0.f, 0.f);
  for (int j = lo; j < hi; j++) {
    float4 v = ((const float4*)(src + (size_t)idx[j] * D))[k4];
    s.x += v.x; s.y += v.y; s.z += v.z; s.w += v.w;
  }
  int c = hi - lo;
  float inv = 1.f / (float)(c > 0 ? c : 1);
  s.x *= inv; s.y *= inv; s.z *= inv; s.w *= inv;
  ushort4 h, l;
  h.x = f2bf(s.x); l.x = f2bf(s.x - bf2f(h.x));
  h.y = f2bf(s.y); l.y = f2bf(s.y - bf2f(h.y));
  h.z = f2bf(s.z); l.z = f2bf(s.z - bf2f(h.z));
  h.w = f2bf(s.w); l.w = f2bf(s.w - bf2f(h.w));
  ((ushort4*)(dh + (size_t)d * D))[k4] = h;
  ((ushort4*)(dl + (size_t)d * D))[k4] = l;
}

// ---------------- plain split for weights ----------------
__global__ void split_kernel(const float* __restrict__ src, unsigned short* __restrict__ dh,
                             unsigned short* __restrict__ dl, int n4) {
  int i = blockIdx.x * 256 + threadIdx.x;
  int stride = gridDim.x * 256;
  for (; i < n4; i += stride) {
    float4 v = ((const float4*)src)[i];
    ushort4 h, l;
    h.x = f2bf(v.x); l.x = f2bf(v.x - bf2f(h.x));
    h.y = f2bf(v.y); l.y = f2bf(v.y - bf2f(h.y));
    h.z = f2bf(v.z); l.z = f2bf(v.z - bf2f(h.z));
    h.w = f2bf(v.w); l.w = f2bf(v.w - bf2f(h.w));
    ((ushort4*)dh)[i] = h;
    ((ushort4*)dl)[i] = l;
  }
}

// ---------------- split-bf16 x3 MFMA NT GEMM (partial, split-K=2) ----------------
// Counted-vmcnt pipeline: 2 staged tiles in flight, raw s_barrier, never drain
// vmcnt to 0 in steady state (T3/T4-minimal; see catalog).
#define GBM 128
#define GBN 128
#define GBK 32

#define GLDS(g, l)                                                             \
  __builtin_amdgcn_global_load_lds(                                            \
      (const __attribute__((address_space(1))) void*)(g),                      \
      (__attribute__((address_space(3))) void*)(l), 16, 0, 0)

#define BAR()                                                                  \
  {                                                                            \
    asm volatile("" ::: "memory");                                             \
    __builtin_amdgcn_s_barrier();                                              \
    asm volatile("" ::: "memory");                                             \
  }

__global__ __launch_bounds__(256, 2) void split_gemm_kernel(
    const unsigned short* __restrict__ Ah, const unsigned short* __restrict__ Al,
    const unsigned short* __restrict__ Bh, const unsigned short* __restrict__ Bl,
    float* __restrict__ P0, float* __restrict__ P1, int Ktot, int Kblk) {
  // 2 buffers x {Ah,Al,Bh,Bl} x [128][32] bf16 (8KB) = 64KB
  __shared__ unsigned short sm[2][4][GBM * GBK];
  const int tid = threadIdx.x;
  const int lane = tid & 63;
  const int wid = tid >> 6;               // 4 waves
  const int wr = wid >> 1, wc = wid & 1;  // wave tile: rows wr*64.., cols wc*64..

  const int bid = blockIdx.x;
  const int kh = bid >> 8;
  const int tile = bid & 255;
  // XCD-chunked swizzle over the 256 output tiles
  const int swz = (tile & 7) * 32 + (tile >> 3);
  const int bm0 = (swz >> 3) * GBM;
  const int bn0 = (swz & 7) * GBN;
  const size_t kbase = (size_t)kh * Kblk;

  // staging: per operand 512 units of 16B; unit u -> LDS offset u*16 (linear).
  // global source k-slot = (u&3) ^ ((r>>1)&3)  [conflict-free involution: 2-way]
  const int u0 = tid, u1 = tid + 256;
  const int r0 = u0 >> 2, r1 = u1 >> 2;
  const int c0 = ((u0 & 3) ^ ((r0 >> 1) & 3)) * 8;
  const int c1 = ((u1 & 3) ^ ((r1 >> 1) & 3)) * 8;

  const unsigned short* gAh0 = Ah + (size_t)(bm0 + r0) * Ktot + kbase + c0;
  const unsigned short* gAh1 = Ah + (size_t)(bm0 + r1) * Ktot + kbase + c1;
  const unsigned short* gAl0 = Al + (size_t)(bm0 + r0) * Ktot + kbase + c0;
  const unsigned short* gAl1 = Al + (size_t)(bm0 + r1) * Ktot + kbase + c1;
  const unsigned short* gBh0 = Bh + (size_t)(bn0 + r0) * Ktot + kbase + c0;
  const unsigned short* gBh1 = Bh + (size_t)(bn0 + r1) * Ktot + kbase + c1;
  const unsigned short* gBl0 = Bl + (size_t)(bn0 + r0) * Ktot + kbase + c0;
  const unsigned short* gBl1 = Bl + (size_t)(bn0 + r1) * Ktot + kbase + c1;

  // ds_read offsets (ushort units): frag row rr, logical k-slot s=lane>>4,
  // physical slot = s ^ ((rr>>1)&3)
  int offA[4], offB[4];
  {
    int s = lane >> 4;
#pragma unroll
    for (int i = 0; i < 4; i++) {
      int rA = wr * 64 + i * 16 + (lane & 15);
      offA[i] = rA * 32 + ((s ^ ((rA >> 1) & 3)) * 8);
      int rB = wc * 64 + i * 16 + (lane & 15);
      offB[i] = rB * 32 + ((s ^ ((rB >> 1) & 3)) * 8);
    }
  }

  f32x4 acc[4][4];
#pragma unroll
  for (int i = 0; i < 4; i++)
#pragma unroll
    for (int j = 0; j < 4; j++) acc[i][j] = (f32x4)(0.f);

  // exactly 8 vmem instructions per STAGE (vmcnt counting relies on this)
#define STAGE(buf)                                                             \
  {                                                                            \
    GLDS(gAh0, &sm[buf][0][u0 * 8]); GLDS(gAh1, &sm[buf][0][u1 * 8]);          \
    GLDS(gAl0, &sm[buf][1][u0 * 8]); GLDS(gAl1, &sm[buf][1][u1 * 8]);          \
    GLDS(gBh0, &sm[buf][2][u0 * 8]); GLDS(gBh1, &sm[buf][2][u1 * 8]);          \
    GLDS(gBl0, &sm[buf][3][u0 * 8]); GLDS(gBl1, &sm[buf][3][u1 * 8]);          \
    gAh0 += GBK; gAh1 += GBK; gAl0 += GBK; gAl1 += GBK;                        \
    gBh0 += GBK; gBh1 += GBK; gBl0 += GBK; gBl1 += GBK;                        \
  }

  const int nt = Kblk / GBK; // >= 16 always
  STAGE(0);
  STAGE(1);
  int cur = 0;
  for (int t = 0; t < nt; t++) {
    // wait: tile t's 8 loads landed; tile t+1's 8 may remain in flight
    if (t < nt - 1) {
      asm volatile("s_waitcnt vmcnt(8)" ::: "memory");
    } else {
      asm volatile("s_waitcnt vmcnt(0)" ::: "memory");
    }
    BAR(); // all waves: sm[cur] fully staged
    short8 fah[4], fal[4], fbh[4], fbl[4];
#pragma unroll
    for (int i = 0; i < 4; i++) {
      fah[i] = *(const short8*)&sm[cur][0][offA[i]];
      fal[i] = *(const short8*)&sm[cur][1][offA[i]];
      fbh[i] = *(const short8*)&sm[cur][2][offB[i]];
      fbl[i] = *(const short8*)&sm[cur][3][offB[i]];
    }
    // three sweeps (hh, hl, lh): 15 independent MFMAs between reuses of one acc
#pragma unroll
    for (int i = 0; i < 4; i++)
#pragma unroll
      for (int j = 0; j < 4; j++)
        acc[i][j] = __builtin_amdgcn_mfma_f32_16x16x32_bf16(fah[i], fbh[j], acc[i][j], 0, 0, 0);
#pragma unroll
    for (int i = 0; i < 4; i++)
#pragma unroll
      for (int j = 0; j < 4; j++)
        acc[i][j] = __builtin_amdgcn_mfma_f32_16x16x32_bf16(fah[i], fbl[j], acc[i][j], 0, 0, 0);
#pragma unroll
    for (int i = 0; i < 4; i++)
#pragma unroll
      for (int j = 0; j < 4; j++)
        acc[i][j] = __builtin_amdgcn_mfma_f32_16x16x32_bf16(fal[i], fbh[j], acc[i][j], 0, 0, 0);
    // all ds_reads of sm[cur] are consumed by MFMAs above (lgkmcnt waits
    // inserted by compiler), so they are complete here.
    BAR(); // all waves done reading sm[cur]
    if (t + 2 < nt) STAGE(cur); // stage tile t+2 into the buffer just freed
    cur ^= 1;
  }

  float* P = kh ? P1 : P0;
  const int rowq = (lane >> 4) * 4;
  const int colq = lane & 15;
#pragma unroll
  for (int i = 0; i < 4; i++) {
#pragma unroll
    for (int j = 0; j < 4; j++) {
#pragma unroll
      for (int q = 0; q < 4; q++) {
        int row = bm0 + wr * 64 + i * 16 + rowq + q;
        int col = bn0 + wc * 64 + j * 16 + colq;
        P[(size_t)row * 1024 + col] = acc[i][j][q];
      }
    }
  }
}

// ---------------- combine: C = leaky(P0+P1+P2+P3 + bias[row]) + hi/lo split ----
__global__ void combine_split_kernel(const float* __restrict__ P0, const float* __restrict__ P1,
                                     const float* __restrict__ P2, const float* __restrict__ P3,
                                     const float* __restrict__ bias, float* __restrict__ Cf,
                                     unsigned short* __restrict__ Ch,
                                     unsigned short* __restrict__ Cl) {
  int i = blockIdx.x * 256 + threadIdx.x; // float4 index, 1M total
  float4 a = ((const float4*)P0)[i];
  float4 b = ((const float4*)P1)[i];
  float4 c = ((const float4*)P2)[i];
  float4 d = ((const float4*)P3)[i];
  float bb = bias[(i * 4) >> 10];
  float4 v;
  v.x = a.x + b.x + c.x + d.x + bb;
  v.y = a.y + b.y + c.y + d.y + bb;
  v.z = a.z + b.z + c.z + d.z + bb;
  v.w = a.w + b.w + c.w + d.w + bb;
  v.x = v.x > 0.f ? v.x : 0.01f * v.x;
  v.y = v.y > 0.f ? v.y : 0.01f * v.y;
  v.z = v.z > 0.f ? v.z : 0.01f * v.z;
  v.w = v.w > 0.f ? v.w : 0.01f * v.w;
  ((float4*)Cf)[i] = v;
  ushort4 h, l;
  h.x = f2bf(v.x); l.x = f2bf(v.x - bf2f(h.x));
  h.y = f2bf(v.y); l.y = f2bf(v.y - bf2f(h.y));
  h.z = f2bf(v.z); l.z = f2bf(v.z - bf2f(h.z));
  h.w = f2bf(v.w); l.w = f2bf(v.w - bf2f(h.w));
  ((ushort4*)Ch)[i] = h;
  ((ushort4*)Cl)[i] = l;
}

// ---------------- combine: C = leaky(P0+P1+P2+P3 + bias[col]) ----------------
__global__ void combine_kernel(const float* __restrict__ P0, const float* __restrict__ P1,
                               const float* __restrict__ P2, const float* __restrict__ P3,
                               const float* __restrict__ bias, float* __restrict__ C) {
  int i = blockIdx.x * 256 + threadIdx.x; // float4 index
  float4 a = ((const float4*)P0)[i];
  float4 b = ((const float4*)P1)[i];
  float4 c = ((const float4*)P2)[i];
  float4 d = ((const float4*)P3)[i];
  float4 bb = *(const float4*)(bias + ((i * 4) & 1023));
  float4 v;
  v.x = a.x + b.x + c.x + d.x + bb.x;
  v.y = a.y + b.y + c.y + d.y + bb.y;
  v.z = a.z + b.z + c.z + d.z + bb.z;
  v.w = a.w + b.w + c.w + d.w + bb.w;
  v.x = v.x > 0.f ? v.x : 0.01f * v.x;
  v.y = v.y > 0.f ? v.y : 0.01f * v.y;
  v.z = v.z > 0.f ? v.z : 0.01f * v.z;
  v.w = v.w > 0.f ? v.w : 0.01f * v.w;
  ((float4*)C)[i] = v;
}

extern "C" void kernel_launch(void* const* d_in, const int* in_sizes, int n_in,
                              void* d_out, int out_size, void* d_ws, size_t ws_size,
                              hipStream_t stream) {
  const float* x      = (const float*)d_in[0];
  const float* col_Wl = (const float*)d_in[1];
  const float* col_Wr = (const float*)d_in[2];
  const float* col_b  = (const float*)d_in[3];
  const float* row_Wl = (const float*)d_in[4];
  const float* row_Wr = (const float*)d_in[5];
  const float* row_b  = (const float*)d_in[6];
  const int*   knn    = (const int*)d_in[7];   // [2][KNN_E]
  const int*   genet  = (const int*)d_in[8];   // [2][GENET_E]
  float* out = (float*)d_out;

  const size_t MAT = (size_t)COL_DIM * ROW_DIM; // 4M elements
  char* w = (char*)d_ws;
  float* ET  = (float*)w; w += MAT * 4;                 // [1024][4096] fp32
  float* E1  = (float*)w; w += MAT * 4;                 // [4096][1024] fp32
  unsigned short* ETh = (unsigned short*)w; w += MAT * 2;
  unsigned short* ETl = (unsigned short*)w; w += MAT * 2;
  unsigned short* Mh  = (unsigned short*)w; w += MAT * 2; // knn mean [1024][4096]
  unsigned short* Ml  = (unsigned short*)w; w += MAT * 2;
  unsigned short* Gh  = (unsigned short*)w; w += MAT * 2; // genet mean [4096][1024]
  unsigned short* Gl  = (unsigned short*)w; w += MAT * 2;
  unsigned short* E1h = (unsigned short*)w; w += MAT * 2;
  unsigned short* E1l = (unsigned short*)w; w += MAT * 2;
  unsigned short* WAh = (unsigned short*)w; w += (size_t)COL_DIM * COL_DIM * 2; // 32MB
  unsigned short* WAl = (unsigned short*)w; w += (size_t)COL_DIM * COL_DIM * 2; // 32MB
  unsigned short* WBh = (unsigned short*)w; w += (size_t)ROW_DIM * ROW_DIM * 2; // 2MB
  unsigned short* WBl = (unsigned short*)w; w += (size_t)ROW_DIM * ROW_DIM * 2; // 2MB
  float* PP0 = (float*)w; w += MAT * 4;
  float* PP1 = (float*)w; w += MAT * 4;
  float* PP2 = (float*)w; w += MAT * 4;
  float* PP3 = (float*)w; w += MAT * 4;
  int* kcnt = (int*)w; w += 1024 * 4;
  int* kptr = (int*)w; w += 1025 * 4;
  int* kidx = (int*)w; w += KNN_E * 4;
  int* gcnt = (int*)w; w += 4096 * 4;
  int* gptr = (int*)w; w += 4097 * 4;
  int* gidx = (int*)w; w += (size_t)GENET_E * 4;

  // ---- CSR build (deterministic via per-bucket value sort) ----
  hipMemsetAsync(kcnt, 0, 1024 * 4, stream);
  hipMemsetAsync(gcnt, 0, 4096 * 4, stream);
  count_kernel<<<KNN_E / 256, 256, 0, stream>>>(knn + KNN_E, KNN_E, kcnt);
  count_kernel<<<GENET_E / 256, 256, 0, stream>>>(genet + GENET_E, GENET_E, gcnt);
  scan_kernel<<<1, 1024, 0, stream>>>(kcnt, kptr, 1024);
  scan_kernel<<<1, 1024, 0, stream>>>(gcnt, gptr, 4096);
  copy_int_kernel<<<4, 256, 0, stream>>>(kptr, kcnt, 1024);
  copy_int_kernel<<<16, 256, 0, stream>>>(gptr, gcnt, 4096);
  fill_kernel<<<KNN_E / 256, 256, 0, stream>>>(knn, knn + KNN_E, KNN_E, kcnt, kidx);
  fill_kernel<<<GENET_E / 256, 256, 0, stream>>>(genet, genet + GENET_E, GENET_E, gcnt, gidx);
  rank_sort_kernel<<<256, 256, 0, stream>>>(kptr, kidx, 1024);
  rank_sort_kernel<<<1024, 256, 0, stream>>>(gptr, gidx, 4096);

  const float* Ein = x;
  for (int i = 0; i < NUM_LAYERS; i++) {
    const float* cWl = col_Wl + (size_t)i * COL_DIM * COL_DIM;
    const float* cWr = col_Wr + (size_t)i * COL_DIM * COL_DIM;
    const float* cb  = col_b + (size_t)i * COL_DIM;
    const float* rWl = row_Wl + (size_t)i * ROW_DIM * ROW_DIM;
    const float* rWr = row_Wr + (size_t)i * ROW_DIM * ROW_DIM;
    const float* rb  = row_b + (size_t)i * ROW_DIM;

    // ---- column branch: E1 = leaky(cWl@mean_c^T + cWr@Ein^T + cb[row]) ----
    transpose_split_kernel<<<dim3(ROW_DIM / 32, COL_DIM / 32), dim3(32, 8), 0, stream>>>(
        Ein, ET, ETh, ETl, COL_DIM, ROW_DIM);
    agg_mean_split_kernel<<<dim3(COL_DIM / 1024, ROW_DIM), 256, 0, stream>>>(
        ET, Mh, Ml, kptr, kidx, COL_DIM);
    split_kernel<<<2048, 256, 0, stream>>>(cWl, WAh, WAl, COL_DIM * COL_DIM / 4);
    split_gemm_kernel<<<512, 256, 0, stream>>>(WAh, WAl, Mh, Ml, PP0, PP1,
                                               COL_DIM, COL_DIM / 2);
    split_kernel<<<2048, 256, 0, stream>>>(cWr, WAh, WAl, COL_DIM * COL_DIM / 4);
    split_gemm_kernel<<<512, 256, 0, stream>>>(WAh, WAl, ETh, ETl, PP2, PP3,
                                               COL_DIM, COL_DIM / 2);
    combine_split_kernel<<<4096, 256, 0, stream>>>(PP0, PP1, PP2, PP3, cb, E1, E1h, E1l);

    // ---- row branch: out = leaky(mean_g@rWl^T + E1@rWr^T + rb[col]) ----
    agg_mean_split_kernel<<<dim3(ROW_DIM / 1024, COL_DIM), 256, 0, stream>>>(
        E1, Gh, Gl, gptr, gidx, ROW_DIM);
    split_kernel<<<1024, 256, 0, stream>>>(rWl, WBh, WBl, ROW_DIM * ROW_DIM / 4);
    split_gemm_kernel<<<512, 256, 0, stream>>>(Gh, Gl, WBh, WBl, PP0, PP1,
                                               ROW_DIM, ROW_DIM / 2);
    split_kernel<<<1024, 256, 0, stream>>>(rWr, WBh, WBl, ROW_DIM * ROW_DIM / 4);
    split_gemm_kernel<<<512, 256, 0, stream>>>(E1h, E1l, WBh, WBl, PP2, PP3,
                                               ROW_DIM, ROW_DIM / 2);
    combine_kernel<<<4096, 256, 0, stream>>>(PP0, PP1, PP2, PP3, rb, out);

    Ein = out;
  }
}

// Round 6
// 1231.334 us; speedup vs baseline: 3.4002x; 1.0710x over previous
//
#include <hip/hip_runtime.h>

#define COL_DIM 4096
#define ROW_DIM 1024
#define NUM_LAYERS 3
#define KNN_E 16384
#define GENET_E 131072

typedef __attribute__((ext_vector_type(8))) short short8;
typedef __attribute__((ext_vector_type(4))) float f32x4;

// ---------------- fp32 -> bf16 hi/lo helpers ----------------
__device__ inline unsigned short f2bf(float f) {
  unsigned int u = __float_as_uint(f);
  u += 0x7FFFu + ((u >> 16) & 1u); // RNE
  return (unsigned short)(u >> 16);
}
__device__ inline float bf2f(unsigned short h) {
  return __uint_as_float(((unsigned int)h) << 16);
}
__device__ inline void cvt8(float4 a, float4 b, short8& h, short8& l) {
  float f[8] = {a.x, a.y, a.z, a.w, b.x, b.y, b.z, b.w};
#pragma unroll
  for (int e = 0; e < 8; e++) {
    unsigned short hh = f2bf(f[e]);
    h[e] = (short)hh;
    l[e] = (short)f2bf(f[e] - bf2f(hh));
  }
}

// ---------------- transpose + split: in[R][C] -> outf/outh/outl [C][R] --------
__global__ void transpose_split_kernel(const float* __restrict__ in,
                                       float* __restrict__ outf,
                                       unsigned short* __restrict__ outh,
                                       unsigned short* __restrict__ outl,
                                       int R, int C) {
  __shared__ float tile[32][33];
  int c0 = blockIdx.x * 32, r0 = blockIdx.y * 32;
  int tx = threadIdx.x, ty = threadIdx.y; // 32 x 8
#pragma unroll
  for (int i = 0; i < 32; i += 8)
    tile[ty + i][tx] = in[(size_t)(r0 + ty + i) * C + c0 + tx];
  __syncthreads();
#pragma unroll
  for (int i = 0; i < 32; i += 8) {
    float v = tile[tx][ty + i];
    size_t o = (size_t)(c0 + ty + i) * R + r0 + tx;
    outf[o] = v;
    unsigned short h = f2bf(v);
    outh[o] = h;
    outl[o] = f2bf(v - bf2f(h));
  }
}

// ---------------- CSR build ----------------
__global__ void count_kernel(const int* __restrict__ dst, int E, int* __restrict__ cnt) {
  int e = blockIdx.x * 256 + threadIdx.x;
  if (e < E) atomicAdd(&cnt[dst[e]], 1);
}

__global__ void scan_kernel(const int* __restrict__ cnt, int* __restrict__ indptr, int n) {
  __shared__ int s[1024];
  __shared__ int base_s;
  int tid = threadIdx.x;
  if (tid == 0) { base_s = 0; indptr[0] = 0; }
  __syncthreads();
  for (int c = 0; c < n; c += 1024) {
    int i = c + tid;
    int v = (i < n) ? cnt[i] : 0;
    s[tid] = v;
    __syncthreads();
    for (int off = 1; off < 1024; off <<= 1) {
      int t = (tid >= off) ? s[tid - off] : 0;
      __syncthreads();
      s[tid] += t;
      __syncthreads();
    }
    if (i < n) indptr[i + 1] = base_s + s[tid];
    __syncthreads();
    if (tid == 0) base_s += s[1023];
    __syncthreads();
  }
}

__global__ void copy_int_kernel(const int* __restrict__ a, int* __restrict__ b, int n) {
  int i = blockIdx.x * 256 + threadIdx.x;
  if (i < n) b[i] = a[i];
}

__global__ void fill_kernel(const int* __restrict__ src, const int* __restrict__ dst, int E,
                            int* __restrict__ cursor, int* __restrict__ idx) {
  int e = blockIdx.x * 256 + threadIdx.x;
  if (e < E) {
    int p = atomicAdd(&cursor[dst[e]], 1);
    idx[p] = src[e];
  }
}

// ---------------- wave-per-bucket rank sort (deterministic: sorted by value) ---
__global__ void rank_sort_kernel(const int* __restrict__ indptr, int* __restrict__ idx,
                                 int n) {
  int wv = threadIdx.x >> 6, lane = threadIdx.x & 63;
  int b = blockIdx.x * (blockDim.x >> 6) + wv;
  if (b >= n) return;
  int lo = indptr[b];
  int d = indptr[b + 1] - lo;
  if (d <= 1) return;
  if (d <= 256) {
    int v0 = (lane < d) ? idx[lo + lane] : 0x7fffffff;
    int v1 = (64 + lane < d) ? idx[lo + 64 + lane] : 0x7fffffff;
    int v2 = (128 + lane < d) ? idx[lo + 128 + lane] : 0x7fffffff;
    int v3 = (192 + lane < d) ? idx[lo + 192 + lane] : 0x7fffffff;
    int r0 = 0, r1 = 0, r2 = 0, r3 = 0;
    for (int j = 0; j < d; j++) {
      int q = j >> 6;
      int sel = (q == 0) ? v0 : (q == 1) ? v1 : (q == 2) ? v2 : v3;
      int bj = __shfl(sel, j & 63);
      r0 += (bj < v0 || (bj == v0 && j < lane)) ? 1 : 0;
      r1 += (bj < v1 || (bj == v1 && j < 64 + lane)) ? 1 : 0;
      r2 += (bj < v2 || (bj == v2 && j < 128 + lane)) ? 1 : 0;
      r3 += (bj < v3 || (bj == v3 && j < 192 + lane)) ? 1 : 0;
    }
    if (lane < d) idx[lo + r0] = v0;
    if (64 + lane < d) idx[lo + r1] = v1;
    if (128 + lane < d) idx[lo + r2] = v2;
    if (192 + lane < d) idx[lo + r3] = v3;
  } else if (lane == 0) {
    for (int i = lo + 1; i < lo + d; i++) {
      int v = idx[i];
      int j = i - 1;
      while (j >= lo && idx[j] > v) { idx[j + 1] = idx[j]; j--; }
      idx[j + 1] = v;
    }
  }
}

// ---------------- neighbor mean, XCD-sliced, + split to bf16 hi/lo ------------
// gridDim.x = 8 column slices -> bid%8 = slice -> each XCD's L2 caches only its
// 2MB source slice (fits 4MB); gathers become L2 hits.
// tprsh: log2(threads per dst row) = log2(D/32). knn: 7, genet: 5.
__global__ void agg_slice_kernel(const float* __restrict__ src,
                                 unsigned short* __restrict__ dh,
                                 unsigned short* __restrict__ dl,
                                 const int* __restrict__ indptr,
                                 const int* __restrict__ idx, int D, int tprsh) {
  int tid = threadIdx.x;
  int d = blockIdx.y * (256 >> tprsh) + (tid >> tprsh);
  int k4 = blockIdx.x * (1 << tprsh) + (tid & ((1 << tprsh) - 1));
  int lo = indptr[d], hi = indptr[d + 1];
  float4 s = make_float4(0.f, 0.f, 0.f, 0.f);
  for (int j = lo; j < hi; j++) {
    float4 v = ((const float4*)(src + (size_t)idx[j] * D))[k4];
    s.x += v.x; s.y += v.y; s.z += v.z; s.w += v.w;
  }
  int c = hi - lo;
  float inv = 1.f / (float)(c > 0 ? c : 1);
  s.x *= inv; s.y *= inv; s.z *= inv; s.w *= inv;
  ushort4 h, l;
  h.x = f2bf(s.x); l.x = f2bf(s.x - bf2f(h.x));
  h.y = f2bf(s.y); l.y = f2bf(s.y - bf2f(h.y));
  h.z = f2bf(s.z); l.z = f2bf(s.z - bf2f(h.z));
  h.w = f2bf(s.w); l.w = f2bf(s.w - bf2f(h.w));
  ((ushort4*)(dh + (size_t)d * D))[k4] = h;
  ((ushort4*)(dl + (size_t)d * D))[k4] = l;
}

// ---------------- dual split-bf16 x3 MFMA NT GEMM ----------------
// P_kh[m][n] = sum_k Op(kh,A)[m,k] * Op(kh,B)[n,k]; kh = bid>>8 selects the
// (A1,B1) or (A2,B2) product (split-K boundary == concat boundary).
// AF32=1: A-side fp32 (weights), staged raw + converted in-register to hi/lo.
//         B-side bf16 hi/lo.  AF32=0: roles swapped.
// 256 thr = 4 waves, 128x128 tile, wave tile 64x64. 64KB LDS, 2 blocks/CU.
#define GBM 128
#define GBN 128
#define GBK 32

#define GLDS(g, l)                                                             \
  __builtin_amdgcn_global_load_lds(                                            \
      (const __attribute__((address_space(1))) void*)(g),                      \
      (__attribute__((address_space(3))) void*)(l), 16, 0, 0)

#define BAR()                                                                  \
  {                                                                            \
    asm volatile("" ::: "memory");                                             \
    __builtin_amdgcn_s_barrier();                                              \
    asm volatile("" ::: "memory");                                             \
  }

#define SWEEPS(AH, AL, BH, BL)                                                 \
  {                                                                            \
    _Pragma("unroll") for (int i = 0; i < 4; i++)                              \
        _Pragma("unroll") for (int j = 0; j < 4; j++)                          \
            acc[i][j] = __builtin_amdgcn_mfma_f32_16x16x32_bf16(               \
                AH[i], BH[j], acc[i][j], 0, 0, 0);                             \
    _Pragma("unroll") for (int i = 0; i < 4; i++)                              \
        _Pragma("unroll") for (int j = 0; j < 4; j++)                          \
            acc[i][j] = __builtin_amdgcn_mfma_f32_16x16x32_bf16(               \
                AH[i], BL[j], acc[i][j], 0, 0, 0);                             \
    _Pragma("unroll") for (int i = 0; i < 4; i++)                              \
        _Pragma("unroll") for (int j = 0; j < 4; j++)                          \
            acc[i][j] = __builtin_amdgcn_mfma_f32_16x16x32_bf16(               \
                AL[i], BH[j], acc[i][j], 0, 0, 0);                             \
  }

template <int AF32>
__global__ __launch_bounds__(256, 2) void dual_gemm_kernel(
    const float* __restrict__ Af1, const float* __restrict__ Af2,
    const unsigned short* __restrict__ Ah1, const unsigned short* __restrict__ Al1,
    const unsigned short* __restrict__ Ah2, const unsigned short* __restrict__ Al2,
    const float* __restrict__ Bf1, const float* __restrict__ Bf2,
    const unsigned short* __restrict__ Bh1, const unsigned short* __restrict__ Bl1,
    const unsigned short* __restrict__ Bh2, const unsigned short* __restrict__ Bl2,
    float* __restrict__ P0, float* __restrict__ P1, int Kloc) {
  // per buffer 32KB: [0,16K) = A-side, [16K,32K) = B-side.
  // fp32 side: 4096 floats. bf16 side: h at +0 (4096 us), l at +8KB.
  __shared__ char smraw[2][32768];
  const int tid = threadIdx.x;
  const int lane = tid & 63;
  const int wid = tid >> 6;
  const int wr = wid >> 1, wc = wid & 1;

  const int bid = blockIdx.x;
  const int kh = bid >> 8;
  const int tile = bid & 255;
  const int swz = (tile & 7) * 32 + (tile >> 3); // XCD-chunked
  const int bm0 = (swz >> 3) * GBM;
  const int bn0 = (swz & 7) * GBN;

  // staging geometry. fp32 operand: 1024 units of 16B, 4/thread, row = 8 units,
  // source slot = (q ^ (r&7)). bf16 operand: 512 units per h/l, 2/thread,
  // row = 4 units, source slot = (q ^ ((r>>1)&3)). Both involutions are
  // re-applied at ds_read -> net identity, conflict-free (2-way max).
  const int u0 = tid, u1 = tid + 256, u2 = tid + 512, u3 = tid + 768;
  const int fr0 = u0 >> 3, fr1 = u1 >> 3, fr2 = u2 >> 3, fr3 = u3 >> 3;
  const int fc0 = ((u0 & 7) ^ (fr0 & 7)) * 4;
  const int fc1 = ((u1 & 7) ^ (fr1 & 7)) * 4;
  const int fc2 = ((u2 & 7) ^ (fr2 & 7)) * 4;
  const int fc3 = ((u3 & 7) ^ (fr3 & 7)) * 4;
  const int hr0 = u0 >> 2, hr1 = u1 >> 2;
  const int hc0 = ((u0 & 3) ^ ((hr0 >> 1) & 3)) * 8;
  const int hc1 = ((u1 & 3) ^ ((hr1 >> 1) & 3)) * 8;

  const float* gF0; const float* gF1; const float* gF2; const float* gF3;
  const unsigned short* gH0; const unsigned short* gH1;
  const unsigned short* gL0; const unsigned short* gL1;
  if constexpr (AF32) {
    const float* Af = kh ? Af2 : Af1;
    const unsigned short* Bh = kh ? Bh2 : Bh1;
    const unsigned short* Bl = kh ? Bl2 : Bl1;
    gF0 = Af + (size_t)(bm0 + fr0) * Kloc + fc0;
    gF1 = Af + (size_t)(bm0 + fr1) * Kloc + fc1;
    gF2 = Af + (size_t)(bm0 + fr2) * Kloc + fc2;
    gF3 = Af + (size_t)(bm0 + fr3) * Kloc + fc3;
    gH0 = Bh + (size_t)(bn0 + hr0) * Kloc + hc0;
    gH1 = Bh + (size_t)(bn0 + hr1) * Kloc + hc1;
    gL0 = Bl + (size_t)(bn0 + hr0) * Kloc + hc0;
    gL1 = Bl + (size_t)(bn0 + hr1) * Kloc + hc1;
  } else {
    const unsigned short* Ah = kh ? Ah2 : Ah1;
    const unsigned short* Al = kh ? Al2 : Al1;
    const float* Bf = kh ? Bf2 : Bf1;
    gH0 = Ah + (size_t)(bm0 + hr0) * Kloc + hc0;
    gH1 = Ah + (size_t)(bm0 + hr1) * Kloc + hc1;
    gL0 = Al + (size_t)(bm0 + hr0) * Kloc + hc0;
    gL1 = Al + (size_t)(bm0 + hr1) * Kloc + hc1;
    gF0 = Bf + (size_t)(bn0 + fr0) * Kloc + fc0;
    gF1 = Bf + (size_t)(bn0 + fr1) * Kloc + fc1;
    gF2 = Bf + (size_t)(bn0 + fr2) * Kloc + fc2;
    gF3 = Bf + (size_t)(bn0 + fr3) * Kloc + fc3;
  }
  const int FB = AF32 ? 0 : 16384;      // byte base of fp32 region
  const int HB = AF32 ? 16384 : 0;      // byte base of bf16 h region

  // always exactly 8 GLDS per STAGE (vmcnt counting depends on it)
  auto STAGE = [&](int buf) {
    char* base = &smraw[buf][0];
    GLDS(gF0, base + FB + u0 * 16); GLDS(gF1, base + FB + u1 * 16);
    GLDS(gF2, base + FB + u2 * 16); GLDS(gF3, base + FB + u3 * 16);
    GLDS(gH0, base + HB + u0 * 16); GLDS(gH1, base + HB + u1 * 16);
    GLDS(gL0, base + HB + 8192 + u0 * 16); GLDS(gL1, base + HB + 8192 + u1 * 16);
    gF0 += GBK; gF1 += GBK; gF2 += GBK; gF3 += GBK;
    gH0 += GBK; gH1 += GBK; gL0 += GBK; gL1 += GBK;
  };

  // fragment ds_read offsets
  int offH[4];         // bf16 side, ushort units
  int offF[4][2];      // fp32 side, float units (2 x float4 per frag)
  {
    int s = lane >> 4;
#pragma unroll
    for (int i = 0; i < 4; i++) {
      int rh = (AF32 ? wc : wr) * 64 + i * 16 + (lane & 15);
      offH[i] = rh * 32 + ((s ^ ((rh >> 1) & 3)) * 8);
      int rf = (AF32 ? wr : wc) * 64 + i * 16 + (lane & 15);
      offF[i][0] = rf * 32 + (((2 * s) ^ (rf & 7)) * 4);
      offF[i][1] = rf * 32 + (((2 * s + 1) ^ (rf & 7)) * 4);
    }
  }

  f32x4 acc[4][4];
#pragma unroll
  for (int i = 0; i < 4; i++)
#pragma unroll
    for (int j = 0; j < 4; j++) acc[i][j] = (f32x4)(0.f);

  const int nt = Kloc / GBK;
  STAGE(0);
  STAGE(1);
  int cur = 0;
  for (int t = 0; t < nt; t++) {
    if (t < nt - 1) {
      asm volatile("s_waitcnt vmcnt(8)" ::: "memory"); // tile t landed
    } else {
      asm volatile("s_waitcnt vmcnt(0)" ::: "memory");
    }
    BAR();
    const float* smF = (const float*)&smraw[cur][FB];
    const unsigned short* smH = (const unsigned short*)&smraw[cur][HB];
    const unsigned short* smL = smH + 4096;
    short8 cvh[4], cvl[4], rdh[4], rdl[4];
#pragma unroll
    for (int i = 0; i < 4; i++) {
      float4 a = *(const float4*)&smF[offF[i][0]];
      float4 b = *(const float4*)&smF[offF[i][1]];
      cvt8(a, b, cvh[i], cvl[i]);
      rdh[i] = *(const short8*)&smH[offH[i]];
      rdl[i] = *(const short8*)&smL[offH[i]];
    }
    __builtin_amdgcn_s_setprio(1);
    if constexpr (AF32) {
      SWEEPS(cvh, cvl, rdh, rdl);   // A = converted fp32, B = bf16 pair
    } else {
      SWEEPS(rdh, rdl, cvh, cvl);   // A = bf16 pair, B = converted fp32
    }
    __builtin_amdgcn_s_setprio(0);
    BAR(); // all waves done reading sm[cur]
    if (t + 2 < nt) STAGE(cur);
    cur ^= 1;
  }

  float* P = kh ? P1 : P0;
  const int rowq = (lane >> 4) * 4;
  const int colq = lane & 15;
#pragma unroll
  for (int i = 0; i < 4; i++) {
#pragma unroll
    for (int j = 0; j < 4; j++) {
#pragma unroll
      for (int q = 0; q < 4; q++) {
        int row = bm0 + wr * 64 + i * 16 + rowq + q;
        int col = bn0 + wc * 64 + j * 16 + colq;
        P[(size_t)row * 1024 + col] = acc[i][j][q];
      }
    }
  }
}

// ---------------- combine: C = leaky(P0+P1 + bias[row]) + hi/lo split ----------
__global__ void combine_split_kernel(const float* __restrict__ P0, const float* __restrict__ P1,
                                     const float* __restrict__ bias, float* __restrict__ Cf,
                                     unsigned short* __restrict__ Ch,
                                     unsigned short* __restrict__ Cl) {
  int i = blockIdx.x * 256 + threadIdx.x; // float4 index, 1M total
  float4 a = ((const float4*)P0)[i];
  float4 b = ((const float4*)P1)[i];
  float bb = bias[(i * 4) >> 10];
  float4 v;
  v.x = a.x + b.x + bb;
  v.y = a.y + b.y + bb;
  v.z = a.z + b.z + bb;
  v.w = a.w + b.w + bb;
  v.x = v.x > 0.f ? v.x : 0.01f * v.x;
  v.y = v.y > 0.f ? v.y : 0.01f * v.y;
  v.z = v.z > 0.f ? v.z : 0.01f * v.z;
  v.w = v.w > 0.f ? v.w : 0.01f * v.w;
  ((float4*)Cf)[i] = v;
  ushort4 h, l;
  h.x = f2bf(v.x); l.x = f2bf(v.x - bf2f(h.x));
  h.y = f2bf(v.y); l.y = f2bf(v.y - bf2f(h.y));
  h.z = f2bf(v.z); l.z = f2bf(v.z - bf2f(h.z));
  h.w = f2bf(v.w); l.w = f2bf(v.w - bf2f(h.w));
  ((ushort4*)Ch)[i] = h;
  ((ushort4*)Cl)[i] = l;
}

// ---------------- combine: C = leaky(P0+P1 + bias[col]) ----------------
__global__ void combine_kernel(const float* __restrict__ P0, const float* __restrict__ P1,
                               const float* __restrict__ bias, float* __restrict__ C) {
  int i = blockIdx.x * 256 + threadIdx.x;
  float4 a = ((const float4*)P0)[i];
  float4 b = ((const float4*)P1)[i];
  float4 bb = *(const float4*)(bias + ((i * 4) & 1023));
  float4 v;
  v.x = a.x + b.x + bb.x;
  v.y = a.y + b.y + bb.y;
  v.z = a.z + b.z + bb.z;
  v.w = a.w + b.w + bb.w;
  v.x = v.x > 0.f ? v.x : 0.01f * v.x;
  v.y = v.y > 0.f ? v.y : 0.01f * v.y;
  v.z = v.z > 0.f ? v.z : 0.01f * v.z;
  v.w = v.w > 0.f ? v.w : 0.01f * v.w;
  ((float4*)C)[i] = v;
}

extern "C" void kernel_launch(void* const* d_in, const int* in_sizes, int n_in,
                              void* d_out, int out_size, void* d_ws, size_t ws_size,
                              hipStream_t stream) {
  const float* x      = (const float*)d_in[0];
  const float* col_Wl = (const float*)d_in[1];
  const float* col_Wr = (const float*)d_in[2];
  const float* col_b  = (const float*)d_in[3];
  const float* row_Wl = (const float*)d_in[4];
  const float* row_Wr = (const float*)d_in[5];
  const float* row_b  = (const float*)d_in[6];
  const int*   knn    = (const int*)d_in[7];   // [2][KNN_E]
  const int*   genet  = (const int*)d_in[8];   // [2][GENET_E]
  float* out = (float*)d_out;

  const size_t MAT = (size_t)COL_DIM * ROW_DIM; // 4M elements
  char* w = (char*)d_ws;
  float* ET  = (float*)w; w += MAT * 4;                   // [1024][4096]
  float* E1  = (float*)w; w += MAT * 4;                   // [4096][1024]
  unsigned short* ETh = (unsigned short*)w; w += MAT * 2;
  unsigned short* ETl = (unsigned short*)w; w += MAT * 2;
  unsigned short* Mh  = (unsigned short*)w; w += MAT * 2; // knn mean [1024][4096]
  unsigned short* Ml  = (unsigned short*)w; w += MAT * 2;
  unsigned short* Gh  = (unsigned short*)w; w += MAT * 2; // genet mean [4096][1024]
  unsigned short* Gl  = (unsigned short*)w; w += MAT * 2;
  unsigned short* E1h = (unsigned short*)w; w += MAT * 2;
  unsigned short* E1l = (unsigned short*)w; w += MAT * 2;
  float* PP0 = (float*)w; w += MAT * 4;
  float* PP1 = (float*)w; w += MAT * 4;
  int* kcnt = (int*)w; w += 1024 * 4;
  int* kptr = (int*)w; w += 1025 * 4;
  int* kidx = (int*)w; w += KNN_E * 4;
  int* gcnt = (int*)w; w += 4096 * 4;
  int* gptr = (int*)w; w += 4097 * 4;
  int* gidx = (int*)w; w += (size_t)GENET_E * 4;

  // ---- CSR build (deterministic via per-bucket value sort) ----
  hipMemsetAsync(kcnt, 0, 1024 * 4, stream);
  hipMemsetAsync(gcnt, 0, 4096 * 4, stream);
  count_kernel<<<KNN_E / 256, 256, 0, stream>>>(knn + KNN_E, KNN_E, kcnt);
  count_kernel<<<GENET_E / 256, 256, 0, stream>>>(genet + GENET_E, GENET_E, gcnt);
  scan_kernel<<<1, 1024, 0, stream>>>(kcnt, kptr, 1024);
  scan_kernel<<<1, 1024, 0, stream>>>(gcnt, gptr, 4096);
  copy_int_kernel<<<4, 256, 0, stream>>>(kptr, kcnt, 1024);
  copy_int_kernel<<<16, 256, 0, stream>>>(gptr, gcnt, 4096);
  fill_kernel<<<KNN_E / 256, 256, 0, stream>>>(knn, knn + KNN_E, KNN_E, kcnt, kidx);
  fill_kernel<<<GENET_E / 256, 256, 0, stream>>>(genet, genet + GENET_E, GENET_E, gcnt, gidx);
  rank_sort_kernel<<<256, 256, 0, stream>>>(kptr, kidx, 1024);
  rank_sort_kernel<<<1024, 256, 0, stream>>>(gptr, gidx, 4096);

  const float* Ein = x;
  for (int i = 0; i < NUM_LAYERS; i++) {
    const float* cWl = col_Wl + (size_t)i * COL_DIM * COL_DIM;
    const float* cWr = col_Wr + (size_t)i * COL_DIM * COL_DIM;
    const float* cb  = col_b + (size_t)i * COL_DIM;
    const float* rWl = row_Wl + (size_t)i * ROW_DIM * ROW_DIM;
    const float* rWr = row_Wr + (size_t)i * ROW_DIM * ROW_DIM;
    const float* rb  = row_b + (size_t)i * ROW_DIM;

    // ---- column branch: E1 = leaky(cWl@M^T + cWr@ET^T + cb[row]) ----
    transpose_split_kernel<<<dim3(ROW_DIM / 32, COL_DIM / 32), dim3(32, 8), 0, stream>>>(
        Ein, ET, ETh, ETl, COL_DIM, ROW_DIM);
    agg_slice_kernel<<<dim3(8, 512), 256, 0, stream>>>(ET, Mh, Ml, kptr, kidx,
                                                       COL_DIM, 7);
    dual_gemm_kernel<1><<<512, 256, 0, stream>>>(
        cWl, cWr, nullptr, nullptr, nullptr, nullptr,
        nullptr, nullptr, Mh, Ml, ETh, ETl, PP0, PP1, COL_DIM);
    combine_split_kernel<<<4096, 256, 0, stream>>>(PP0, PP1, cb, E1, E1h, E1l);

    // ---- row branch: out = leaky(G@rWl^T + E1@rWr^T + rb[col]) ----
    agg_slice_kernel<<<dim3(8, 512), 256, 0, stream>>>(E1, Gh, Gl, gptr, gidx,
                                                       ROW_DIM, 5);
    dual_gemm_kernel<0><<<512, 256, 0, stream>>>(
        nullptr, nullptr, Gh, Gl, E1h, E1l,
        rWl, rWr, nullptr, nullptr, nullptr, nullptr, PP0, PP1, ROW_DIM);
    combine_kernel<<<4096, 256, 0, stream>>>(PP0, PP1, rb, out);

    Ein = out;
  }
}